// Round 2
// baseline (705.628 us; speedup 1.0000x reference)
//
#include <hip/hip_runtime.h>
#include <hip/hip_bf16.h>
#include <math.h>

#define IN_F 256
#define OUT_F 128
#define HEADS 4
#define HF 512   // HEADS*OUT_F

typedef __hip_bfloat16 bf16;

__device__ __forceinline__ float bflo(unsigned u) { return __uint_as_float(u << 16); }
__device__ __forceinline__ float bfhi(unsigned u) { return __uint_as_float(u & 0xffff0000u); }

__device__ __forceinline__ void store_c(float* p, float v) { *p = v; }
__device__ __forceinline__ void store_c(bf16* p, float v) { *p = __float2bfloat16(v); }

// ---------------- GEMM: C[M,N] = A[M,K] @ B[K,N] (+ bias[N]) ----------------
template <typename OT>
__global__ __launch_bounds__(256) void gemm_bias(
    const float* __restrict__ A, const float* __restrict__ B,
    const float* __restrict__ bias, OT* __restrict__ C,
    int M, int N, int K) {
    const int BM = 64, BN = 64, BK = 32;
    __shared__ float As[BK][BM + 1];
    __shared__ float Bs[BK][BN + 1];
    int tid = threadIdx.x;
    int tr = tid >> 4, tc = tid & 15;          // 16x16 thread grid, 4x4 micro
    int brow = blockIdx.y * BM, bcol = blockIdx.x * BN;
    float acc[4][4] = {};
    for (int k0 = 0; k0 < K; k0 += BK) {
        #pragma unroll
        for (int t = tid; t < BM * BK; t += 256) {
            int m = t >> 5, k = t & 31;
            As[k][m] = A[(size_t)(brow + m) * K + k0 + k];
        }
        #pragma unroll
        for (int t = tid; t < BK * BN; t += 256) {
            int k = t >> 6, n = t & 63;
            Bs[k][n] = B[(size_t)(k0 + k) * N + bcol + n];
        }
        __syncthreads();
        #pragma unroll
        for (int k = 0; k < BK; ++k) {
            float a[4], b[4];
            #pragma unroll
            for (int i = 0; i < 4; i++) a[i] = As[k][tr * 4 + i];
            #pragma unroll
            for (int j = 0; j < 4; j++) b[j] = Bs[k][tc * 4 + j];
            #pragma unroll
            for (int i = 0; i < 4; i++)
                #pragma unroll
                for (int j = 0; j < 4; j++)
                    acc[i][j] = fmaf(a[i], b[j], acc[i][j]);
        }
        __syncthreads();
    }
    #pragma unroll
    for (int i = 0; i < 4; i++) {
        int r = brow + tr * 4 + i;
        #pragma unroll
        for (int j = 0; j < 4; j++) {
            int c = bcol + tc * 4 + j;
            float v = acc[i][j];
            if (bias) v += bias[c];
            store_c(&C[(size_t)r * N + c], v);
        }
    }
}

// ---------------- GAT edge pipeline (bf16 tables, no max pass) ----------------
// wave per edge. lane l covers features f=8l..8l+7 (head h=l>>4, cols (l&15)*8..).
// score = att . leaky0.2(xl[src]+xr[dst]); writes exp(score) + denom atomics.
__global__ __launch_bounds__(256) void edge_score_kernel(
    const bf16* __restrict__ xl, const bf16* __restrict__ xr,
    const int* __restrict__ ei, const float* __restrict__ att,
    float* __restrict__ score, float* __restrict__ denom, int E, int N) {
    int wid = (blockIdx.x * 256 + threadIdx.x) >> 6;
    int lane = threadIdx.x & 63;
    int Etot = E + N;
    if (wid >= Etot) return;
    int src, dst;
    if (wid < E) { src = ei[wid]; dst = ei[E + wid]; }
    else         { src = dst = wid - E; }
    const uint4 lv = ((const uint4*)(xl + (size_t)src * HF))[lane];
    const uint4 rv = ((const uint4*)(xr + (size_t)dst * HF))[lane];
    const float4 a0 = ((const float4*)att)[lane * 2];
    const float4 a1 = ((const float4*)att)[lane * 2 + 1];
    float e[8];
    e[0] = bflo(lv.x) + bflo(rv.x); e[1] = bfhi(lv.x) + bfhi(rv.x);
    e[2] = bflo(lv.y) + bflo(rv.y); e[3] = bfhi(lv.y) + bfhi(rv.y);
    e[4] = bflo(lv.z) + bflo(rv.z); e[5] = bfhi(lv.z) + bfhi(rv.z);
    e[6] = bflo(lv.w) + bflo(rv.w); e[7] = bfhi(lv.w) + bfhi(rv.w);
    const float aw[8] = {a0.x, a0.y, a0.z, a0.w, a1.x, a1.y, a1.z, a1.w};
    float s = 0.f;
    #pragma unroll
    for (int j = 0; j < 8; ++j) {
        float v = e[j] > 0.f ? e[j] : 0.2f * e[j];
        s = fmaf(v, aw[j], s);
    }
    // reduce within 16-lane (per-head) groups
    #pragma unroll
    for (int off = 1; off < 16; off <<= 1) s += __shfl_xor(s, off);
    if ((lane & 15) == 0) {
        int h = lane >> 4;
        float ex = __expf(s);
        score[(size_t)wid * HEADS + h] = ex;
        atomicAdd(&denom[dst * HEADS + h], ex);
    }
}

// wave per edge: hgat[dst, c] += sum_h 0.25 * alpha[h] * xl[src,h,c]
__global__ __launch_bounds__(256) void edge_agg_kernel(
    const bf16* __restrict__ xl, const int* __restrict__ ei,
    const float* __restrict__ score, const float* __restrict__ denom,
    float* __restrict__ hgat, int E, int N) {
    int wid = (blockIdx.x * 256 + threadIdx.x) >> 6;
    int lane = threadIdx.x & 63;
    int Etot = E + N;
    if (wid >= Etot) return;
    int src, dst;
    if (wid < E) { src = ei[wid]; dst = ei[E + wid]; }
    else         { src = dst = wid - E; }
    int h = lane >> 4;
    float alpha = 0.25f * score[(size_t)wid * HEADS + h] / denom[dst * HEADS + h];
    const uint4 lv = ((const uint4*)(xl + (size_t)src * HF))[lane];
    float c[8];
    c[0] = bflo(lv.x); c[1] = bfhi(lv.x);
    c[2] = bflo(lv.y); c[3] = bfhi(lv.y);
    c[4] = bflo(lv.z); c[5] = bfhi(lv.z);
    c[6] = bflo(lv.w); c[7] = bfhi(lv.w);
    #pragma unroll
    for (int j = 0; j < 8; ++j) c[j] *= alpha;
    // fold the 4 heads: lanes {l, l^16, l^32, l^48} share the same 8 cols
    #pragma unroll
    for (int j = 0; j < 8; ++j) {
        c[j] += __shfl_xor(c[j], 16);
        c[j] += __shfl_xor(c[j], 32);
    }
    // each quartet member writes 2 of the 8 columns
    int j0 = 2 * h;
    int col = (lane & 15) * 8 + j0;
    float* dstp = hgat + (size_t)dst * 128 + col;
    atomicAdd(dstp,     c[j0]);
    atomicAdd(dstp + 1, c[j0 + 1]);
}

// ---------------- conv branch ----------------
__global__ void transpose_w_kernel(const float* __restrict__ W, float* __restrict__ Wt) {
    int idx = blockIdx.x * 256 + threadIdx.x;
    if (idx >= 128 * 128 * 7) return;
    int o = idx / 896, rem = idx % 896, i = rem / 7, k = rem % 7;
    Wt[((size_t)k * 128 + i) * 128 + o] = W[idx];
}

__global__ __launch_bounds__(256) void conv1d_kernel(
    const float* __restrict__ xc, const float* __restrict__ Wt,
    float* __restrict__ hc) {
    __shared__ float lds[128 * 24];
    int b = blockIdx.y;
    int l0 = blockIdx.x * 16;
    int tid = threadIdx.x;
    int i = tid & 127, r0 = tid >> 7;
    for (int r = r0; r < 22; r += 2) {
        int l = l0 - 3 + r;
        float v = (l >= 0 && l < 512) ? xc[((size_t)b * 512 + l) * 128 + i] : 0.f;
        lds[i * 24 + r] = v;
    }
    __syncthreads();
    int o = tid & 127, lp = tid >> 7;
    float acc[8] = {};
    for (int ii = 0; ii < 128; ++ii) {
        float xv[21];
        #pragma unroll
        for (int r = 0; r < 21; ++r) xv[r] = lds[ii * 24 + lp + r];
        #pragma unroll
        for (int k = 0; k < 7; ++k) {
            float w = Wt[((size_t)k * 128 + ii) * 128 + o];
            #pragma unroll
            for (int j = 0; j < 8; ++j)
                acc[j] = fmaf(w, xv[2 * j + k], acc[j]);
        }
    }
    #pragma unroll
    for (int j = 0; j < 8; ++j) {
        int l = l0 + lp + 2 * j;
        hc[((size_t)b * 512 + l) * 128 + o] = acc[j];
    }
}

// ---------------- layernorm epilogues ----------------
__global__ __launch_bounds__(256) void post_ln_kernel(
    float* __restrict__ buf, const float* __restrict__ bias,
    const float* __restrict__ gamma, const float* __restrict__ beta,
    float slope, int N) {
    int wid = (blockIdx.x * 256 + threadIdx.x) >> 6;
    int lane = threadIdx.x & 63;
    if (wid >= N) return;
    float* row = buf + (size_t)wid * 128;
    float v0 = row[lane], v1 = row[lane + 64];
    if (bias) { v0 += bias[lane]; v1 += bias[lane + 64]; }
    v0 = v0 > 0.f ? v0 : slope * v0;
    v1 = v1 > 0.f ? v1 : slope * v1;
    float s = v0 + v1;
    #pragma unroll
    for (int off = 32; off; off >>= 1) s += __shfl_xor(s, off);
    float mu = s * (1.f / 128.f);
    float d0 = v0 - mu, d1 = v1 - mu;
    float vs = d0 * d0 + d1 * d1;
    #pragma unroll
    for (int off = 32; off; off >>= 1) vs += __shfl_xor(vs, off);
    float inv = rsqrtf(vs * (1.f / 128.f) + 1e-5f);
    row[lane]      = d0 * inv * gamma[lane]      + beta[lane];
    row[lane + 64] = d1 * inv * gamma[lane + 64] + beta[lane + 64];
}

__global__ __launch_bounds__(256) void fuse_ln_kernel(
    const float* __restrict__ a, const float* __restrict__ b2,
    const float* __restrict__ c, const float* __restrict__ gamma,
    const float* __restrict__ beta, float* __restrict__ out, int N) {
    int wid = (blockIdx.x * 256 + threadIdx.x) >> 6;
    int lane = threadIdx.x & 63;
    if (wid >= N) return;
    size_t base = (size_t)wid * 128;
    float v0 = a[base + lane]      + b2[base + lane]      + c[base + lane];
    float v1 = a[base + lane + 64] + b2[base + lane + 64] + c[base + lane + 64];
    float s = v0 + v1;
    #pragma unroll
    for (int off = 32; off; off >>= 1) s += __shfl_xor(s, off);
    float mu = s * (1.f / 128.f);
    float d0 = v0 - mu, d1 = v1 - mu;
    float vs = d0 * d0 + d1 * d1;
    #pragma unroll
    for (int off = 32; off; off >>= 1) vs += __shfl_xor(vs, off);
    float inv = rsqrtf(vs * (1.f / 128.f) + 1e-5f);
    out[base + lane]      = d0 * inv * gamma[lane]      + beta[lane];
    out[base + lane + 64] = d1 * inv * gamma[lane + 64] + beta[lane + 64];
}

extern "C" void kernel_launch(void* const* d_in, const int* in_sizes, int n_in,
                              void* d_out, int out_size, void* d_ws, size_t ws_size,
                              hipStream_t stream) {
    const float* x         = (const float*)d_in[0];
    const int*   ei        = (const int*)d_in[1];
    const float* W_l       = (const float*)d_in[2];
    const float* W_r       = (const float*)d_in[3];
    const float* att       = (const float*)d_in[4];
    const float* gat_bias  = (const float*)d_in[5];
    const float* gat_gamma = (const float*)d_in[6];
    const float* gat_beta  = (const float*)d_in[7];
    const float* cnn_W     = (const float*)d_in[8];
    const float* cnn_b     = (const float*)d_in[9];
    const float* conv_W    = (const float*)d_in[10];
    const float* conv_b    = (const float*)d_in[11];
    const float* cnn_gamma = (const float*)d_in[12];
    const float* cnn_beta  = (const float*)d_in[13];
    const float* res_W     = (const float*)d_in[14];
    const float* res_b     = (const float*)d_in[15];
    const float* fuse_gamma= (const float*)d_in[16];
    const float* fuse_beta = (const float*)d_in[17];

    int N = in_sizes[0] / IN_F;   // 16384
    int E = in_sizes[1] / 2;      // 262144
    int Etot = E + N;

    // workspace layout
    char* ws = (char*)d_ws;
    size_t off = 0;
    bf16* xlb   = (bf16*)(ws + off); off += (size_t)N * HF * 2;        // 16MB
    bf16* xrb   = (bf16*)(ws + off); off += (size_t)N * HF * 2;        // 16MB
    float* score= (float*)(ws + off); off += (size_t)Etot * HEADS * 4; // 4.5MB
    float* denom= (float*)(ws + off); off += (size_t)N * HEADS * 4;
    float* hgat = (float*)(ws + off); off += (size_t)N * 128 * 4;      // 8MB
    float* res  = (float*)(ws + off); off += (size_t)N * 128 * 4;
    float* hc   = (float*)(ws + off); off += (size_t)N * 128 * 4;
    float* xc   = (float*)(ws + off); off += (size_t)N * 128 * 4;
    float* Wt   = (float*)(ws + off); off += (size_t)128 * 128 * 7 * 4;

    hipMemsetAsync(denom, 0, (size_t)N * HEADS * 4, stream);
    hipMemsetAsync(hgat,  0, (size_t)N * 128 * 4,   stream);

    dim3 blk(256);
    // projections (bf16 outputs for the edge phase)
    gemm_bias<bf16><<<dim3(HF / 64, N / 64), blk, 0, stream>>>(x, W_l, nullptr, xlb, N, HF, IN_F);
    gemm_bias<bf16><<<dim3(HF / 64, N / 64), blk, 0, stream>>>(x, W_r, nullptr, xrb, N, HF, IN_F);
    transpose_w_kernel<<<(128 * 128 * 7 + 255) / 256, blk, 0, stream>>>(conv_W, Wt);

    // GAT pipeline (no max pass: softmax shift-invariant, scores bounded)
    int wblocks = (Etot + 3) / 4;
    edge_score_kernel<<<wblocks, blk, 0, stream>>>(xlb, xrb, ei, att, score, denom, E, N);
    edge_agg_kernel<<<wblocks, blk, 0, stream>>>(xlb, ei, score, denom, hgat, E, N);

    // CNN + residual branch
    gemm_bias<float><<<dim3(128 / 64, N / 64), blk, 0, stream>>>(x, cnn_W, cnn_b, xc, N, 128, IN_F);
    gemm_bias<float><<<dim3(128 / 64, N / 64), blk, 0, stream>>>(x, res_W, res_b, res, N, 128, IN_F);
    conv1d_kernel<<<dim3(512 / 16, N / 512), blk, 0, stream>>>(xc, Wt, hc);

    // epilogues
    post_ln_kernel<<<(N + 3) / 4, blk, 0, stream>>>(hgat, gat_bias, gat_gamma, gat_beta, 0.01f, N);
    post_ln_kernel<<<(N + 3) / 4, blk, 0, stream>>>(hc, conv_b, cnn_gamma, cnn_beta, 0.0f, N);
    fuse_ln_kernel<<<(N + 3) / 4, blk, 0, stream>>>(hgat, hc, res, fuse_gamma, fuse_beta,
                                                    (float*)d_out, N);
}

// Round 3
// 485.723 us; speedup vs baseline: 1.4527x; 1.4527x over previous
//
#include <hip/hip_runtime.h>
#include <hip/hip_bf16.h>
#include <math.h>

#define IN_F 256
#define OUT_F 128
#define HEADS 4
#define HF 512   // HEADS*OUT_F

typedef __hip_bfloat16 bf16;

__device__ __forceinline__ float bflo(unsigned u) { return __uint_as_float(u << 16); }
__device__ __forceinline__ float bfhi(unsigned u) { return __uint_as_float(u & 0xffff0000u); }

__device__ __forceinline__ void store_c(float* p, float v) { *p = v; }
__device__ __forceinline__ void store_c(bf16* p, float v) { *p = __float2bfloat16(v); }

// ---------------- GEMM: C[M,N] = A[M,K] @ B[K,N] (+ bias[N]) ----------------
template <typename OT>
__global__ __launch_bounds__(256) void gemm_bias(
    const float* __restrict__ A, const float* __restrict__ B,
    const float* __restrict__ bias, OT* __restrict__ C,
    int M, int N, int K) {
    const int BM = 64, BN = 64, BK = 32;
    __shared__ float As[BK][BM + 1];
    __shared__ float Bs[BK][BN + 1];
    int tid = threadIdx.x;
    int tr = tid >> 4, tc = tid & 15;          // 16x16 thread grid, 4x4 micro
    int brow = blockIdx.y * BM, bcol = blockIdx.x * BN;
    float acc[4][4] = {};
    for (int k0 = 0; k0 < K; k0 += BK) {
        #pragma unroll
        for (int t = tid; t < BM * BK; t += 256) {
            int m = t >> 5, k = t & 31;
            As[k][m] = A[(size_t)(brow + m) * K + k0 + k];
        }
        #pragma unroll
        for (int t = tid; t < BK * BN; t += 256) {
            int k = t >> 6, n = t & 63;
            Bs[k][n] = B[(size_t)(k0 + k) * N + bcol + n];
        }
        __syncthreads();
        #pragma unroll
        for (int k = 0; k < BK; ++k) {
            float a[4], b[4];
            #pragma unroll
            for (int i = 0; i < 4; i++) a[i] = As[k][tr * 4 + i];
            #pragma unroll
            for (int j = 0; j < 4; j++) b[j] = Bs[k][tc * 4 + j];
            #pragma unroll
            for (int i = 0; i < 4; i++)
                #pragma unroll
                for (int j = 0; j < 4; j++)
                    acc[i][j] = fmaf(a[i], b[j], acc[i][j]);
        }
        __syncthreads();
    }
    #pragma unroll
    for (int i = 0; i < 4; i++) {
        int r = brow + tr * 4 + i;
        #pragma unroll
        for (int j = 0; j < 4; j++) {
            int c = bcol + tc * 4 + j;
            float v = acc[i][j];
            if (bias) v += bias[c];
            store_c(&C[(size_t)r * N + c], v);
        }
    }
}

// ---------------- CSR build (counting sort by dst) ----------------
__global__ __launch_bounds__(256) void hist_kernel(
    const int* __restrict__ ei, int* __restrict__ counts, int E) {
    int e = blockIdx.x * 256 + threadIdx.x;
    if (e < E) atomicAdd(&counts[ei[E + e]], 1);
}

// single block, 1024 threads, 16 elems/thread: exclusive scan of counts[N]
__global__ __launch_bounds__(1024) void scan_kernel(
    const int* __restrict__ counts, int* __restrict__ offs,
    int* __restrict__ cursor, int N) {
    __shared__ int lsum[1024];
    int t = threadIdx.x;
    int base = t * 16;
    int local[16];
    int s = 0;
    #pragma unroll
    for (int i = 0; i < 16; ++i) {
        int v = (base + i < N) ? counts[base + i] : 0;
        local[i] = v; s += v;
    }
    lsum[t] = s;
    __syncthreads();
    for (int d = 1; d < 1024; d <<= 1) {
        int v = 0;
        if (t >= d) v = lsum[t - d];
        __syncthreads();
        if (t >= d) lsum[t] += v;
        __syncthreads();
    }
    int run = (t ? lsum[t - 1] : 0);
    #pragma unroll
    for (int i = 0; i < 16; ++i) {
        if (base + i < N) { offs[base + i] = run; cursor[base + i] = run; }
        run += local[i];
    }
}

__global__ __launch_bounds__(256) void scatter_kernel(
    const int* __restrict__ ei, int* __restrict__ cursor,
    int* __restrict__ srcs, int E) {
    int e = blockIdx.x * 256 + threadIdx.x;
    if (e < E) {
        int d = ei[E + e];
        int p = atomicAdd(&cursor[d], 1);
        srcs[p] = ei[e];
    }
}

// ---------------- fused GAT: score + online softmax + aggregate ----------------
// wave per dst node. lane covers feats f=8*lane..8*lane+7 (head h=lane>>4).
// hgat[d, c] = 0.25 * sum_h ( sum_e ex_e*xl[src_e,h,c] ) / ( sum_e ex_e )
__global__ __launch_bounds__(256) void gat_fused_kernel(
    const bf16* __restrict__ xl, const bf16* __restrict__ xr,
    const int* __restrict__ srcs, const int* __restrict__ offs,
    const float* __restrict__ att, float* __restrict__ hgat,
    int E, int N) {
    int wid = (blockIdx.x * 256 + threadIdx.x) >> 6;
    int lane = threadIdx.x & 63;
    if (wid >= N) return;
    int d = wid;
    const uint4 rv = ((const uint4*)(xr + (size_t)d * HF))[lane];
    float xr8[8];
    xr8[0] = bflo(rv.x); xr8[1] = bfhi(rv.x);
    xr8[2] = bflo(rv.y); xr8[3] = bfhi(rv.y);
    xr8[4] = bflo(rv.z); xr8[5] = bfhi(rv.z);
    xr8[6] = bflo(rv.w); xr8[7] = bfhi(rv.w);
    const float4 a0 = ((const float4*)att)[lane * 2];
    const float4 a1 = ((const float4*)att)[lane * 2 + 1];
    const float aw[8] = {a0.x, a0.y, a0.z, a0.w, a1.x, a1.y, a1.z, a1.w};
    float acc[8] = {};
    float dn = 0.f;

    auto process = [&](uint4 lv) {
        float xl8[8];
        xl8[0] = bflo(lv.x); xl8[1] = bfhi(lv.x);
        xl8[2] = bflo(lv.y); xl8[3] = bfhi(lv.y);
        xl8[4] = bflo(lv.z); xl8[5] = bfhi(lv.z);
        xl8[6] = bflo(lv.w); xl8[7] = bfhi(lv.w);
        float s = 0.f;
        #pragma unroll
        for (int j = 0; j < 8; ++j) {
            float v = xl8[j] + xr8[j];
            v = v > 0.f ? v : 0.2f * v;
            s = fmaf(v, aw[j], s);
        }
        #pragma unroll
        for (int off = 1; off < 16; off <<= 1) s += __shfl_xor(s, off);
        float ex = __expf(s);
        dn += ex;
        #pragma unroll
        for (int j = 0; j < 8; ++j) acc[j] = fmaf(ex, xl8[j], acc[j]);
    };

    // self-loop (always present)
    process(((const uint4*)(xl + (size_t)d * HF))[lane]);

    int start = offs[d];
    int end = (d == N - 1) ? E : offs[d + 1];
    int p = start;
    for (; p + 1 < end; p += 2) {          // 2-deep pipeline for gather ILP
        int s0 = srcs[p], s1 = srcs[p + 1];
        uint4 l0 = ((const uint4*)(xl + (size_t)s0 * HF))[lane];
        uint4 l1 = ((const uint4*)(xl + (size_t)s1 * HF))[lane];
        process(l0);
        process(l1);
    }
    if (p < end)
        process(((const uint4*)(xl + (size_t)srcs[p] * HF))[lane]);

    float inv = 1.f / dn;
    float v[8];
    #pragma unroll
    for (int j = 0; j < 8; ++j) {
        float t2 = acc[j] * inv;
        t2 += __shfl_xor(t2, 16);
        t2 += __shfl_xor(t2, 32);
        v[j] = t2;
    }
    int h = lane >> 4;
    int col = (lane & 15) * 8 + 2 * h;
    float2 outv = make_float2(0.25f * v[2 * h], 0.25f * v[2 * h + 1]);
    *(float2*)(hgat + (size_t)d * 128 + col) = outv;
}

// ---------------- conv branch ----------------
__global__ void transpose_w_kernel(const float* __restrict__ W, float* __restrict__ Wt) {
    int idx = blockIdx.x * 256 + threadIdx.x;
    if (idx >= 128 * 128 * 7) return;
    int o = idx / 896, rem = idx % 896, i = rem / 7, k = rem % 7;
    Wt[((size_t)k * 128 + i) * 128 + o] = W[idx];
}

__global__ __launch_bounds__(256) void conv1d_kernel(
    const float* __restrict__ xc, const float* __restrict__ Wt,
    float* __restrict__ hc) {
    __shared__ float lds[128 * 24];
    int b = blockIdx.y;
    int l0 = blockIdx.x * 16;
    int tid = threadIdx.x;
    int i = tid & 127, r0 = tid >> 7;
    for (int r = r0; r < 22; r += 2) {
        int l = l0 - 3 + r;
        float v = (l >= 0 && l < 512) ? xc[((size_t)b * 512 + l) * 128 + i] : 0.f;
        lds[i * 24 + r] = v;
    }
    __syncthreads();
    int o = tid & 127, lp = tid >> 7;
    float acc[8] = {};
    for (int ii = 0; ii < 128; ++ii) {
        float xv[21];
        #pragma unroll
        for (int r = 0; r < 21; ++r) xv[r] = lds[ii * 24 + lp + r];
        #pragma unroll
        for (int k = 0; k < 7; ++k) {
            float w = Wt[((size_t)k * 128 + ii) * 128 + o];
            #pragma unroll
            for (int j = 0; j < 8; ++j)
                acc[j] = fmaf(w, xv[2 * j + k], acc[j]);
        }
    }
    #pragma unroll
    for (int j = 0; j < 8; ++j) {
        int l = l0 + lp + 2 * j;
        hc[((size_t)b * 512 + l) * 128 + o] = acc[j];
    }
}

// ---------------- layernorm epilogues ----------------
__global__ __launch_bounds__(256) void post_ln_kernel(
    float* __restrict__ buf, const float* __restrict__ bias,
    const float* __restrict__ gamma, const float* __restrict__ beta,
    float slope, int N) {
    int wid = (blockIdx.x * 256 + threadIdx.x) >> 6;
    int lane = threadIdx.x & 63;
    if (wid >= N) return;
    float* row = buf + (size_t)wid * 128;
    float v0 = row[lane], v1 = row[lane + 64];
    if (bias) { v0 += bias[lane]; v1 += bias[lane + 64]; }
    v0 = v0 > 0.f ? v0 : slope * v0;
    v1 = v1 > 0.f ? v1 : slope * v1;
    float s = v0 + v1;
    #pragma unroll
    for (int off = 32; off; off >>= 1) s += __shfl_xor(s, off);
    float mu = s * (1.f / 128.f);
    float d0 = v0 - mu, d1 = v1 - mu;
    float vs = d0 * d0 + d1 * d1;
    #pragma unroll
    for (int off = 32; off; off >>= 1) vs += __shfl_xor(vs, off);
    float inv = rsqrtf(vs * (1.f / 128.f) + 1e-5f);
    row[lane]      = d0 * inv * gamma[lane]      + beta[lane];
    row[lane + 64] = d1 * inv * gamma[lane + 64] + beta[lane + 64];
}

__global__ __launch_bounds__(256) void fuse_ln_kernel(
    const float* __restrict__ a, const float* __restrict__ b2,
    const float* __restrict__ c, const float* __restrict__ gamma,
    const float* __restrict__ beta, float* __restrict__ out, int N) {
    int wid = (blockIdx.x * 256 + threadIdx.x) >> 6;
    int lane = threadIdx.x & 63;
    if (wid >= N) return;
    size_t base = (size_t)wid * 128;
    float v0 = a[base + lane]      + b2[base + lane]      + c[base + lane];
    float v1 = a[base + lane + 64] + b2[base + lane + 64] + c[base + lane + 64];
    float s = v0 + v1;
    #pragma unroll
    for (int off = 32; off; off >>= 1) s += __shfl_xor(s, off);
    float mu = s * (1.f / 128.f);
    float d0 = v0 - mu, d1 = v1 - mu;
    float vs = d0 * d0 + d1 * d1;
    #pragma unroll
    for (int off = 32; off; off >>= 1) vs += __shfl_xor(vs, off);
    float inv = rsqrtf(vs * (1.f / 128.f) + 1e-5f);
    out[base + lane]      = d0 * inv * gamma[lane]      + beta[lane];
    out[base + lane + 64] = d1 * inv * gamma[lane + 64] + beta[lane + 64];
}

extern "C" void kernel_launch(void* const* d_in, const int* in_sizes, int n_in,
                              void* d_out, int out_size, void* d_ws, size_t ws_size,
                              hipStream_t stream) {
    const float* x         = (const float*)d_in[0];
    const int*   ei        = (const int*)d_in[1];
    const float* W_l       = (const float*)d_in[2];
    const float* W_r       = (const float*)d_in[3];
    const float* att       = (const float*)d_in[4];
    const float* gat_bias  = (const float*)d_in[5];
    const float* gat_gamma = (const float*)d_in[6];
    const float* gat_beta  = (const float*)d_in[7];
    const float* cnn_W     = (const float*)d_in[8];
    const float* cnn_b     = (const float*)d_in[9];
    const float* conv_W    = (const float*)d_in[10];
    const float* conv_b    = (const float*)d_in[11];
    const float* cnn_gamma = (const float*)d_in[12];
    const float* cnn_beta  = (const float*)d_in[13];
    const float* res_W     = (const float*)d_in[14];
    const float* res_b     = (const float*)d_in[15];
    const float* fuse_gamma= (const float*)d_in[16];
    const float* fuse_beta = (const float*)d_in[17];

    int N = in_sizes[0] / IN_F;   // 16384
    int E = in_sizes[1] / 2;      // 262144

    // workspace layout
    char* ws = (char*)d_ws;
    size_t off = 0;
    bf16* xlb    = (bf16*)(ws + off); off += (size_t)N * HF * 2;       // 16MB
    bf16* xrb    = (bf16*)(ws + off); off += (size_t)N * HF * 2;       // 16MB
    int*  counts = (int*)(ws + off);  off += (size_t)N * 4;
    int*  offs   = (int*)(ws + off);  off += (size_t)N * 4;
    int*  cursor = (int*)(ws + off);  off += (size_t)N * 4;
    int*  srcs   = (int*)(ws + off);  off += (size_t)E * 4;            // 1MB
    float* hgat  = (float*)(ws + off); off += (size_t)N * 128 * 4;     // 8MB
    float* res   = (float*)(ws + off); off += (size_t)N * 128 * 4;
    float* hc    = (float*)(ws + off); off += (size_t)N * 128 * 4;
    float* xc    = (float*)(ws + off); off += (size_t)N * 128 * 4;
    float* Wt    = (float*)(ws + off); off += (size_t)128 * 128 * 7 * 4;

    hipMemsetAsync(counts, 0, (size_t)N * 4, stream);

    dim3 blk(256);
    // CSR build
    hist_kernel<<<(E + 255) / 256, blk, 0, stream>>>(ei, counts, E);
    scan_kernel<<<1, 1024, 0, stream>>>(counts, offs, cursor, N);
    scatter_kernel<<<(E + 255) / 256, blk, 0, stream>>>(ei, cursor, srcs, E);

    // projections (bf16 outputs for the edge phase)
    gemm_bias<bf16><<<dim3(HF / 64, N / 64), blk, 0, stream>>>(x, W_l, nullptr, xlb, N, HF, IN_F);
    gemm_bias<bf16><<<dim3(HF / 64, N / 64), blk, 0, stream>>>(x, W_r, nullptr, xrb, N, HF, IN_F);
    transpose_w_kernel<<<(128 * 128 * 7 + 255) / 256, blk, 0, stream>>>(conv_W, Wt);

    // fused GAT (no atomics, online softmax)
    gat_fused_kernel<<<(N + 3) / 4, blk, 0, stream>>>(xlb, xrb, srcs, offs, att, hgat, E, N);

    // CNN + residual branch
    gemm_bias<float><<<dim3(128 / 64, N / 64), blk, 0, stream>>>(x, cnn_W, cnn_b, xc, N, 128, IN_F);
    gemm_bias<float><<<dim3(128 / 64, N / 64), blk, 0, stream>>>(x, res_W, res_b, res, N, 128, IN_F);
    conv1d_kernel<<<dim3(512 / 16, N / 512), blk, 0, stream>>>(xc, Wt, hc);

    // epilogues
    post_ln_kernel<<<(N + 3) / 4, blk, 0, stream>>>(hgat, gat_bias, gat_gamma, gat_beta, 0.01f, N);
    post_ln_kernel<<<(N + 3) / 4, blk, 0, stream>>>(hc, conv_b, cnn_gamma, cnn_beta, 0.0f, N);
    fuse_ln_kernel<<<(N + 3) / 4, blk, 0, stream>>>(hgat, hc, res, fuse_gamma, fuse_beta,
                                                    (float*)d_out, N);
}

// Round 4
// 239.324 us; speedup vs baseline: 2.9484x; 2.0296x over previous
//
#include <hip/hip_runtime.h>
#include <hip/hip_bf16.h>
#include <math.h>

#define IN_F 256
#define OUT_F 128
#define HEADS 4
#define HF 512    // HEADS*OUT_F
#define NCAT 1280 // 512 + 512 + 128 + 128

typedef __hip_bfloat16 bf16;
typedef unsigned short ushort_t;

using bf16x8 = __attribute__((ext_vector_type(8))) short;
using f32x4  = __attribute__((ext_vector_type(4))) float;

__device__ __forceinline__ float bflo(unsigned u) { return __uint_as_float(u << 16); }
__device__ __forceinline__ float bfhi(unsigned u) { return __uint_as_float(u & 0xffff0000u); }
__device__ __forceinline__ float bf2f(ushort_t u) { return __uint_as_float((unsigned)u << 16); }
__device__ __forceinline__ ushort_t f2bf(float f) {
    __hip_bfloat16 h = __float2bfloat16(f);
    return *reinterpret_cast<ushort_t*>(&h);
}

// ---------------- input conversions ----------------
// x fp32 -> bf16, 8 elems/thread
__global__ __launch_bounds__(256) void cvt_x_kernel(
    const float* __restrict__ x, ushort_t* __restrict__ xb, int n) {
    int i = (blockIdx.x * 256 + threadIdx.x) * 8;
    if (i >= n) return;
    float4 a = *(const float4*)(x + i);
    float4 b = *(const float4*)(x + i + 4);
    uint4 o;
    o.x = f2bf(a.x) | ((unsigned)f2bf(a.y) << 16);
    o.y = f2bf(a.z) | ((unsigned)f2bf(a.w) << 16);
    o.z = f2bf(b.x) | ((unsigned)f2bf(b.y) << 16);
    o.w = f2bf(b.z) | ((unsigned)f2bf(b.w) << 16);
    *(uint4*)(xb + i) = o;
}

// Wt[n][k] (bf16) = concat(W_l, W_r, cnn_W, res_W)[k][n]
__global__ __launch_bounds__(256) void build_wt_kernel(
    const float* __restrict__ Wl, const float* __restrict__ Wr,
    const float* __restrict__ Wc, const float* __restrict__ Wres,
    ushort_t* __restrict__ Wt) {
    int idx = blockIdx.x * 256 + threadIdx.x;   // n*256 + k
    if (idx >= NCAT * 256) return;
    int n = idx >> 8, k = idx & 255;
    float v;
    if (n < 512)       v = Wl[(size_t)k * 512 + n];
    else if (n < 1024) v = Wr[(size_t)k * 512 + (n - 512)];
    else if (n < 1152) v = Wc[(size_t)k * 128 + (n - 1024)];
    else               v = Wres[(size_t)k * 128 + (n - 1152)];
    Wt[idx] = f2bf(v);
}

// ---------------- fused MFMA GEMM: cat[M][1280] = xb[M][256] @ Wcat ----------------
__global__ __launch_bounds__(256) void mfma_gemm(
    const ushort_t* __restrict__ A,   // [M][256] bf16
    const ushort_t* __restrict__ Wt,  // [1280][256] bf16 (pre-transposed)
    ushort_t* __restrict__ C,         // [M][1280] bf16
    int M) {
    __shared__ ushort_t As[128][40];  // +8 pad: row stride 80B = 5*16B
    __shared__ ushort_t Bs[128][40];
    int tid = threadIdx.x;
    int lane = tid & 63, wid = tid >> 6;
    int wr = (wid >> 1) * 64, wc = (wid & 1) * 64;
    int brow = blockIdx.y * 128, bcol = blockIdx.x * 128;
    f32x4 acc[4][4] = {};
    int kb = (lane >> 4) * 8;
    int rl = lane & 15;
    for (int k0 = 0; k0 < 256; k0 += 32) {
        #pragma unroll
        for (int i = 0; i < 2; ++i) {
            int idx = tid + 256 * i;
            int row = idx >> 2, seg = idx & 3;
            *(uint4*)&As[row][seg * 8] =
                *(const uint4*)(A + (size_t)(brow + row) * 256 + k0 + seg * 8);
            *(uint4*)&Bs[row][seg * 8] =
                *(const uint4*)(Wt + (size_t)(bcol + row) * 256 + k0 + seg * 8);
        }
        __syncthreads();
        bf16x8 af[4], bf[4];
        #pragma unroll
        for (int m = 0; m < 4; ++m) af[m] = *(const bf16x8*)&As[wr + m * 16 + rl][kb];
        #pragma unroll
        for (int n = 0; n < 4; ++n) bf[n] = *(const bf16x8*)&Bs[wc + n * 16 + rl][kb];
        #pragma unroll
        for (int m = 0; m < 4; ++m)
            #pragma unroll
            for (int n = 0; n < 4; ++n)
                acc[m][n] = __builtin_amdgcn_mfma_f32_16x16x32_bf16(
                    af[m], bf[n], acc[m][n], 0, 0, 0);
        __syncthreads();
    }
    // epilogue: C/D layout col=lane&15, row=(lane>>4)*4+reg  [m89/m91]
    int rowb = (lane >> 4) * 4;
    #pragma unroll
    for (int m = 0; m < 4; ++m)
        #pragma unroll
        for (int n = 0; n < 4; ++n) {
            int col = bcol + wc + n * 16 + rl;
            #pragma unroll
            for (int q = 0; q < 4; ++q) {
                int row = brow + wr + m * 16 + rowb + q;
                C[(size_t)row * NCAT + col] = f2bf(acc[m][n][q]);
            }
        }
}

// ---------------- CSR build (counting sort by dst) ----------------
__global__ __launch_bounds__(256) void hist_kernel(
    const int* __restrict__ ei, int* __restrict__ counts, int E) {
    int e = blockIdx.x * 256 + threadIdx.x;
    if (e < E) atomicAdd(&counts[ei[E + e]], 1);
}

__global__ __launch_bounds__(1024) void scan_kernel(
    const int* __restrict__ counts, int* __restrict__ offs,
    int* __restrict__ cursor, int N) {
    __shared__ int lsum[1024];
    int t = threadIdx.x;
    int base = t * 16;
    int local[16];
    int s = 0;
    #pragma unroll
    for (int i = 0; i < 16; ++i) {
        int v = (base + i < N) ? counts[base + i] : 0;
        local[i] = v; s += v;
    }
    lsum[t] = s;
    __syncthreads();
    for (int d = 1; d < 1024; d <<= 1) {
        int v = 0;
        if (t >= d) v = lsum[t - d];
        __syncthreads();
        if (t >= d) lsum[t] += v;
        __syncthreads();
    }
    int run = (t ? lsum[t - 1] : 0);
    #pragma unroll
    for (int i = 0; i < 16; ++i) {
        if (base + i < N) { offs[base + i] = run; cursor[base + i] = run; }
        run += local[i];
    }
}

__global__ __launch_bounds__(256) void scatter_kernel(
    const int* __restrict__ ei, int* __restrict__ cursor,
    int* __restrict__ srcs, int E) {
    int e = blockIdx.x * 256 + threadIdx.x;
    if (e < E) {
        int d = ei[E + e];
        int p = atomicAdd(&cursor[d], 1);
        srcs[p] = ei[e];
    }
}

// ---------------- fused GAT: score + online softmax + aggregate ----------------
// wave per dst node; xl = cat[:, 0:512], xr = cat[:, 512:1024] (stride NCAT)
__global__ __launch_bounds__(256) void gat_fused_kernel(
    const ushort_t* __restrict__ cat, const int* __restrict__ srcs,
    const int* __restrict__ offs, const float* __restrict__ att,
    float* __restrict__ hgat, int E, int N) {
    int wid = (blockIdx.x * 256 + threadIdx.x) >> 6;
    int lane = threadIdx.x & 63;
    if (wid >= N) return;
    int d = wid;
    const uint4 rv = ((const uint4*)(cat + (size_t)d * NCAT + 512))[lane];
    float xr8[8];
    xr8[0] = bflo(rv.x); xr8[1] = bfhi(rv.x);
    xr8[2] = bflo(rv.y); xr8[3] = bfhi(rv.y);
    xr8[4] = bflo(rv.z); xr8[5] = bfhi(rv.z);
    xr8[6] = bflo(rv.w); xr8[7] = bfhi(rv.w);
    const float4 a0 = ((const float4*)att)[lane * 2];
    const float4 a1 = ((const float4*)att)[lane * 2 + 1];
    const float aw[8] = {a0.x, a0.y, a0.z, a0.w, a1.x, a1.y, a1.z, a1.w};
    float acc[8] = {};
    float dn = 0.f;

    auto process = [&](uint4 lv) {
        float xl8[8];
        xl8[0] = bflo(lv.x); xl8[1] = bfhi(lv.x);
        xl8[2] = bflo(lv.y); xl8[3] = bfhi(lv.y);
        xl8[4] = bflo(lv.z); xl8[5] = bfhi(lv.z);
        xl8[6] = bflo(lv.w); xl8[7] = bfhi(lv.w);
        float s = 0.f;
        #pragma unroll
        for (int j = 0; j < 8; ++j) {
            float v = xl8[j] + xr8[j];
            v = v > 0.f ? v : 0.2f * v;
            s = fmaf(v, aw[j], s);
        }
        #pragma unroll
        for (int off = 1; off < 16; off <<= 1) s += __shfl_xor(s, off);
        float ex = __expf(s);
        dn += ex;
        #pragma unroll
        for (int j = 0; j < 8; ++j) acc[j] = fmaf(ex, xl8[j], acc[j]);
    };

    // self-loop
    process(((const uint4*)(cat + (size_t)d * NCAT))[lane]);

    int start = offs[d];
    int end = (d == N - 1) ? E : offs[d + 1];
    int p = start;
    for (; p + 1 < end; p += 2) {
        int s0 = srcs[p], s1 = srcs[p + 1];
        uint4 l0 = ((const uint4*)(cat + (size_t)s0 * NCAT))[lane];
        uint4 l1 = ((const uint4*)(cat + (size_t)s1 * NCAT))[lane];
        process(l0);
        process(l1);
    }
    if (p < end)
        process(((const uint4*)(cat + (size_t)srcs[p] * NCAT))[lane]);

    float inv = 1.f / dn;
    float v[8];
    #pragma unroll
    for (int j = 0; j < 8; ++j) {
        float t2 = acc[j] * inv;
        t2 += __shfl_xor(t2, 16);
        t2 += __shfl_xor(t2, 32);
        v[j] = t2;
    }
    int h = lane >> 4;
    int col = (lane & 15) * 8 + 2 * h;
    float2 outv = make_float2(0.25f * v[2 * h], 0.25f * v[2 * h + 1]);
    *(float2*)(hgat + (size_t)d * 128 + col) = outv;
}

// ---------------- conv branch ----------------
__global__ void transpose_w_kernel(const float* __restrict__ W, float* __restrict__ Wt) {
    int idx = blockIdx.x * 256 + threadIdx.x;
    if (idx >= 128 * 128 * 7) return;
    int o = idx / 896, rem = idx % 896, i = rem / 7, k = rem % 7;
    Wt[((size_t)k * 128 + i) * 128 + o] = W[idx];
}

// xc = cat[:, 1024:1152] bf16 (+cnn_b at staging); fp32 compute
__global__ __launch_bounds__(256) void conv1d_kernel(
    const ushort_t* __restrict__ cat, const float* __restrict__ cnn_b,
    const float* __restrict__ Wt, float* __restrict__ hc) {
    __shared__ float lds[128 * 24];
    int b = blockIdx.y;
    int l0 = blockIdx.x * 16;
    int tid = threadIdx.x;
    int i = tid & 127, r0 = tid >> 7;
    float bi = cnn_b[i];
    for (int r = r0; r < 22; r += 2) {
        int l = l0 - 3 + r;
        float v = 0.f;
        if (l >= 0 && l < 512)
            v = bf2f(cat[(size_t)(b * 512 + l) * NCAT + 1024 + i]) + bi;
        lds[i * 24 + r] = v;
    }
    __syncthreads();
    int o = tid & 127, lp = tid >> 7;
    float acc[8] = {};
    for (int ii = 0; ii < 128; ++ii) {
        float xv[21];
        #pragma unroll
        for (int r = 0; r < 21; ++r) xv[r] = lds[ii * 24 + lp + r];
        #pragma unroll
        for (int k = 0; k < 7; ++k) {
            float w = Wt[((size_t)k * 128 + ii) * 128 + o];
            #pragma unroll
            for (int j = 0; j < 8; ++j)
                acc[j] = fmaf(w, xv[2 * j + k], acc[j]);
        }
    }
    #pragma unroll
    for (int j = 0; j < 8; ++j) {
        int l = l0 + lp + 2 * j;
        hc[((size_t)b * 512 + l) * 128 + o] = acc[j];
    }
}

// ---------------- layernorm epilogues ----------------
__global__ __launch_bounds__(256) void post_ln_kernel(
    float* __restrict__ buf, const float* __restrict__ bias,
    const float* __restrict__ gamma, const float* __restrict__ beta,
    float slope, int N) {
    int wid = (blockIdx.x * 256 + threadIdx.x) >> 6;
    int lane = threadIdx.x & 63;
    if (wid >= N) return;
    float* row = buf + (size_t)wid * 128;
    float v0 = row[lane], v1 = row[lane + 64];
    if (bias) { v0 += bias[lane]; v1 += bias[lane + 64]; }
    v0 = v0 > 0.f ? v0 : slope * v0;
    v1 = v1 > 0.f ? v1 : slope * v1;
    float s = v0 + v1;
    #pragma unroll
    for (int off = 32; off; off >>= 1) s += __shfl_xor(s, off);
    float mu = s * (1.f / 128.f);
    float d0 = v0 - mu, d1 = v1 - mu;
    float vs = d0 * d0 + d1 * d1;
    #pragma unroll
    for (int off = 32; off; off >>= 1) vs += __shfl_xor(vs, off);
    float inv = rsqrtf(vs * (1.f / 128.f) + 1e-5f);
    row[lane]      = d0 * inv * gamma[lane]      + beta[lane];
    row[lane + 64] = d1 * inv * gamma[lane + 64] + beta[lane + 64];
}

// out = LN(hgat + hc + res + res_b); res = cat[:, 1152:1280] bf16
__global__ __launch_bounds__(256) void fuse_ln_kernel(
    const float* __restrict__ a, const float* __restrict__ b2,
    const ushort_t* __restrict__ cat, const float* __restrict__ resb,
    const float* __restrict__ gamma, const float* __restrict__ beta,
    float* __restrict__ out, int N) {
    int wid = (blockIdx.x * 256 + threadIdx.x) >> 6;
    int lane = threadIdx.x & 63;
    if (wid >= N) return;
    size_t base = (size_t)wid * 128;
    size_t cbase = (size_t)wid * NCAT + 1152;
    float v0 = a[base + lane]      + b2[base + lane]
             + bf2f(cat[cbase + lane])      + resb[lane];
    float v1 = a[base + lane + 64] + b2[base + lane + 64]
             + bf2f(cat[cbase + lane + 64]) + resb[lane + 64];
    float s = v0 + v1;
    #pragma unroll
    for (int off = 32; off; off >>= 1) s += __shfl_xor(s, off);
    float mu = s * (1.f / 128.f);
    float d0 = v0 - mu, d1 = v1 - mu;
    float vs = d0 * d0 + d1 * d1;
    #pragma unroll
    for (int off = 32; off; off >>= 1) vs += __shfl_xor(vs, off);
    float inv = rsqrtf(vs * (1.f / 128.f) + 1e-5f);
    out[base + lane]      = d0 * inv * gamma[lane]      + beta[lane];
    out[base + lane + 64] = d1 * inv * gamma[lane + 64] + beta[lane + 64];
}

extern "C" void kernel_launch(void* const* d_in, const int* in_sizes, int n_in,
                              void* d_out, int out_size, void* d_ws, size_t ws_size,
                              hipStream_t stream) {
    const float* x         = (const float*)d_in[0];
    const int*   ei        = (const int*)d_in[1];
    const float* W_l       = (const float*)d_in[2];
    const float* W_r       = (const float*)d_in[3];
    const float* att       = (const float*)d_in[4];
    const float* gat_bias  = (const float*)d_in[5];
    const float* gat_gamma = (const float*)d_in[6];
    const float* gat_beta  = (const float*)d_in[7];
    const float* cnn_W     = (const float*)d_in[8];
    const float* cnn_b     = (const float*)d_in[9];
    const float* conv_W    = (const float*)d_in[10];
    const float* conv_b    = (const float*)d_in[11];
    const float* cnn_gamma = (const float*)d_in[12];
    const float* cnn_beta  = (const float*)d_in[13];
    const float* res_W     = (const float*)d_in[14];
    const float* res_b     = (const float*)d_in[15];
    const float* fuse_gamma= (const float*)d_in[16];
    const float* fuse_beta = (const float*)d_in[17];

    int N = in_sizes[0] / IN_F;   // 16384
    int E = in_sizes[1] / 2;      // 262144

    // workspace layout
    char* ws = (char*)d_ws;
    size_t off = 0;
    ushort_t* xb   = (ushort_t*)(ws + off); off += (size_t)N * IN_F * 2;     // 8MB
    ushort_t* Wt   = (ushort_t*)(ws + off); off += (size_t)NCAT * IN_F * 2;  // 0.65MB
    ushort_t* cat  = (ushort_t*)(ws + off); off += (size_t)N * NCAT * 2;     // 42MB
    int*  counts   = (int*)(ws + off);  off += (size_t)N * 4;
    int*  offs     = (int*)(ws + off);  off += (size_t)N * 4;
    int*  cursor   = (int*)(ws + off);  off += (size_t)N * 4;
    int*  srcs     = (int*)(ws + off);  off += (size_t)E * 4;                // 1MB
    float* hgat    = (float*)(ws + off); off += (size_t)N * 128 * 4;         // 8MB
    float* hc      = (float*)(ws + off); off += (size_t)N * 128 * 4;         // 8MB
    float* Wtc     = (float*)(ws + off); off += (size_t)128 * 128 * 7 * 4;

    hipMemsetAsync(counts, 0, (size_t)N * 4, stream);

    dim3 blk(256);
    // CSR build
    hist_kernel<<<(E + 255) / 256, blk, 0, stream>>>(ei, counts, E);
    scan_kernel<<<1, 1024, 0, stream>>>(counts, offs, cursor, N);
    scatter_kernel<<<(E + 255) / 256, blk, 0, stream>>>(ei, cursor, srcs, E);

    // operand prep
    cvt_x_kernel<<<(N * IN_F / 8 + 255) / 256, blk, 0, stream>>>(x, xb, N * IN_F);
    build_wt_kernel<<<(NCAT * 256 + 255) / 256, blk, 0, stream>>>(W_l, W_r, cnn_W, res_W, Wt);
    transpose_w_kernel<<<(128 * 128 * 7 + 255) / 256, blk, 0, stream>>>(conv_W, Wtc);

    // one fused MFMA GEMM for all four projections
    mfma_gemm<<<dim3(NCAT / 128, N / 128), blk, 0, stream>>>(xb, Wt, cat, N);

    // fused GAT (no atomics, online softmax)
    gat_fused_kernel<<<(N + 3) / 4, blk, 0, stream>>>(cat, srcs, offs, att, hgat, E, N);

    // conv branch
    conv1d_kernel<<<dim3(512 / 16, N / 512), blk, 0, stream>>>(cat, cnn_b, Wtc, hc);

    // epilogues
    post_ln_kernel<<<(N + 3) / 4, blk, 0, stream>>>(hgat, gat_bias, gat_gamma, gat_beta, 0.01f, N);
    post_ln_kernel<<<(N + 3) / 4, blk, 0, stream>>>(hc, conv_b, cnn_gamma, cnn_beta, 0.0f, N);
    fuse_ln_kernel<<<(N + 3) / 4, blk, 0, stream>>>(hgat, hc, cat, res_b, fuse_gamma, fuse_beta,
                                                    (float*)d_out, N);
}

// Round 5
// 175.861 us; speedup vs baseline: 4.0124x; 1.3609x over previous
//
#include <hip/hip_runtime.h>
#include <hip/hip_bf16.h>
#include <math.h>

#define IN_F 256
#define OUT_F 128
#define HEADS 4
#define HF 512    // HEADS*OUT_F
#define NCAT 1280 // 512 + 512 + 128 + 128

typedef __hip_bfloat16 bf16;
typedef unsigned short ushort_t;

using bf16x8 = __attribute__((ext_vector_type(8))) short;
using f32x4  = __attribute__((ext_vector_type(4))) float;

__device__ __forceinline__ float bflo(unsigned u) { return __uint_as_float(u << 16); }
__device__ __forceinline__ float bfhi(unsigned u) { return __uint_as_float(u & 0xffff0000u); }
__device__ __forceinline__ float bf2f(ushort_t u) { return __uint_as_float((unsigned)u << 16); }
__device__ __forceinline__ ushort_t f2bf(float f) {
    __hip_bfloat16 h = __float2bfloat16(f);
    return *reinterpret_cast<ushort_t*>(&h);
}

// ---------------- input conversions ----------------
__global__ __launch_bounds__(256) void cvt_x_kernel(
    const float* __restrict__ x, ushort_t* __restrict__ xb, int n) {
    int i = (blockIdx.x * 256 + threadIdx.x) * 8;
    if (i >= n) return;
    float4 a = *(const float4*)(x + i);
    float4 b = *(const float4*)(x + i + 4);
    uint4 o;
    o.x = f2bf(a.x) | ((unsigned)f2bf(a.y) << 16);
    o.y = f2bf(a.z) | ((unsigned)f2bf(a.w) << 16);
    o.z = f2bf(b.x) | ((unsigned)f2bf(b.y) << 16);
    o.w = f2bf(b.z) | ((unsigned)f2bf(b.w) << 16);
    *(uint4*)(xb + i) = o;
}

// Wt[n][k] (bf16) = concat(W_l, W_r, cnn_W, res_W)[k][n]
__global__ __launch_bounds__(256) void build_wt_kernel(
    const float* __restrict__ Wl, const float* __restrict__ Wr,
    const float* __restrict__ Wc, const float* __restrict__ Wres,
    ushort_t* __restrict__ Wt) {
    int idx = blockIdx.x * 256 + threadIdx.x;   // n*256 + k
    if (idx >= NCAT * 256) return;
    int n = idx >> 8, k = idx & 255;
    float v;
    if (n < 512)       v = Wl[(size_t)k * 512 + n];
    else if (n < 1024) v = Wr[(size_t)k * 512 + (n - 512)];
    else if (n < 1152) v = Wc[(size_t)k * 128 + (n - 1024)];
    else               v = Wres[(size_t)k * 128 + (n - 1152)];
    Wt[idx] = f2bf(v);
}

// Wt2[k][o][i] (bf16) = conv_W[o][i][k]
__global__ __launch_bounds__(256) void build_wt2_kernel(
    const float* __restrict__ W, ushort_t* __restrict__ Wt2) {
    int idx = blockIdx.x * 256 + threadIdx.x;
    if (idx >= 7 * 128 * 128) return;
    int k = idx >> 14, o = (idx >> 7) & 127, i = idx & 127;
    Wt2[idx] = f2bf(W[((size_t)o * 128 + i) * 7 + k]);
}

// ---------------- fused MFMA GEMM: cat[M][1280] = xb[M][256] @ Wcat ----------------
__global__ __launch_bounds__(256) void mfma_gemm(
    const ushort_t* __restrict__ A,   // [M][256] bf16
    const ushort_t* __restrict__ Wt,  // [1280][256] bf16 (pre-transposed)
    ushort_t* __restrict__ C,         // [M][1280] bf16
    int M) {
    __shared__ ushort_t As[128][40];
    __shared__ ushort_t Bs[128][40];
    int tid = threadIdx.x;
    int lane = tid & 63, wid = tid >> 6;
    int wr = (wid >> 1) * 64, wc = (wid & 1) * 64;
    int brow = blockIdx.y * 128, bcol = blockIdx.x * 128;
    f32x4 acc[4][4] = {};
    int kb = (lane >> 4) * 8;
    int rl = lane & 15;
    for (int k0 = 0; k0 < 256; k0 += 32) {
        #pragma unroll
        for (int i = 0; i < 2; ++i) {
            int idx = tid + 256 * i;
            int row = idx >> 2, seg = idx & 3;
            *(uint4*)&As[row][seg * 8] =
                *(const uint4*)(A + (size_t)(brow + row) * 256 + k0 + seg * 8);
            *(uint4*)&Bs[row][seg * 8] =
                *(const uint4*)(Wt + (size_t)(bcol + row) * 256 + k0 + seg * 8);
        }
        __syncthreads();
        bf16x8 af[4], bf[4];
        #pragma unroll
        for (int m = 0; m < 4; ++m) af[m] = *(const bf16x8*)&As[wr + m * 16 + rl][kb];
        #pragma unroll
        for (int n = 0; n < 4; ++n) bf[n] = *(const bf16x8*)&Bs[wc + n * 16 + rl][kb];
        #pragma unroll
        for (int m = 0; m < 4; ++m)
            #pragma unroll
            for (int n = 0; n < 4; ++n)
                acc[m][n] = __builtin_amdgcn_mfma_f32_16x16x32_bf16(
                    af[m], bf[n], acc[m][n], 0, 0, 0);
        __syncthreads();
    }
    int rowb = (lane >> 4) * 4;
    #pragma unroll
    for (int m = 0; m < 4; ++m)
        #pragma unroll
        for (int n = 0; n < 4; ++n) {
            int col = bcol + wc + n * 16 + rl;
            #pragma unroll
            for (int q = 0; q < 4; ++q) {
                int row = brow + wr + m * 16 + rowb + q;
                C[(size_t)row * NCAT + col] = f2bf(acc[m][n][q]);
            }
        }
}

// ---------------- MFMA conv1d: hc[l,o] = sum_{k,i} xcb[l+k-3,i]*W[o,i,k] ----------------
// grid (8 L-tiles, 32 batches); block 256 = 4 waves (2x2), 64 L-rows x 128 out-chans
__global__ __launch_bounds__(256) void conv_mfma(
    const ushort_t* __restrict__ cat, const float* __restrict__ cnn_b,
    const ushort_t* __restrict__ Wt2, float* __restrict__ hc) {
    __shared__ ushort_t As[70][136];   // rows l0-3 .. l0+66, xc+bias, bf16
    __shared__ ushort_t Bs[128][136];  // Wt2[k]: [o][i]
    int tid = threadIdx.x;
    int lane = tid & 63, wid = tid >> 6;
    int wr = (wid >> 1) * 32, wc = (wid & 1) * 64;
    int b = blockIdx.y, l0 = blockIdx.x * 64;
    // stage A (bias added in-range; pad rows stay exactly 0)
    for (int u = tid; u < 70 * 16; u += 256) {
        int r = u >> 4, seg = u & 15;
        int l = l0 - 3 + r;
        uint4 o4 = make_uint4(0, 0, 0, 0);
        if (l >= 0 && l < 512) {
            uint4 v = *(const uint4*)(cat + (size_t)(b * 512 + l) * NCAT + 1024 + seg * 8);
            float4 b0 = *(const float4*)(cnn_b + seg * 8);
            float4 b1 = *(const float4*)(cnn_b + seg * 8 + 4);
            o4.x = f2bf(bflo(v.x) + b0.x) | ((unsigned)f2bf(bfhi(v.x) + b0.y) << 16);
            o4.y = f2bf(bflo(v.y) + b0.z) | ((unsigned)f2bf(bfhi(v.y) + b0.w) << 16);
            o4.z = f2bf(bflo(v.z) + b1.x) | ((unsigned)f2bf(bfhi(v.z) + b1.y) << 16);
            o4.w = f2bf(bflo(v.w) + b1.z) | ((unsigned)f2bf(bfhi(v.w) + b1.w) << 16);
        }
        *(uint4*)&As[r][seg * 8] = o4;
    }
    f32x4 acc[2][4] = {};
    int rl = lane & 15, kb = (lane >> 4) * 8;
    for (int k = 0; k < 7; ++k) {
        __syncthreads();   // waves done with previous Bs (and As staged, k=0)
        for (int u = tid; u < 128 * 16; u += 256) {
            int r = u >> 4, seg = u & 15;
            *(uint4*)&Bs[r][seg * 8] =
                *(const uint4*)(Wt2 + ((size_t)(k * 128 + r)) * 128 + seg * 8);
        }
        __syncthreads();
        #pragma unroll
        for (int kk = 0; kk < 4; ++kk) {
            bf16x8 af[2], bfr[4];
            af[0] = *(const bf16x8*)&As[wr + 0  + rl + k][kk * 32 + kb];
            af[1] = *(const bf16x8*)&As[wr + 16 + rl + k][kk * 32 + kb];
            #pragma unroll
            for (int n = 0; n < 4; ++n)
                bfr[n] = *(const bf16x8*)&Bs[wc + n * 16 + rl][kk * 32 + kb];
            #pragma unroll
            for (int m = 0; m < 2; ++m)
                #pragma unroll
                for (int n = 0; n < 4; ++n)
                    acc[m][n] = __builtin_amdgcn_mfma_f32_16x16x32_bf16(
                        af[m], bfr[n], acc[m][n], 0, 0, 0);
        }
    }
    int rowb = (lane >> 4) * 4;
    #pragma unroll
    for (int m = 0; m < 2; ++m)
        #pragma unroll
        for (int n = 0; n < 4; ++n) {
            int col = wc + n * 16 + rl;
            #pragma unroll
            for (int q = 0; q < 4; ++q) {
                int l = l0 + wr + m * 16 + rowb + q;
                hc[(size_t)(b * 512 + l) * 128 + col] = acc[m][n][q];
            }
        }
}

// ---------------- CSR build (counting sort by dst) ----------------
__global__ __launch_bounds__(256) void hist_kernel(
    const int* __restrict__ ei, int* __restrict__ counts, int E) {
    int e = blockIdx.x * 256 + threadIdx.x;
    if (e < E) atomicAdd(&counts[ei[E + e]], 1);
}

__global__ __launch_bounds__(1024) void scan_kernel(
    const int* __restrict__ counts, int* __restrict__ offs,
    int* __restrict__ cursor, int N) {
    __shared__ int lsum[1024];
    int t = threadIdx.x;
    int base = t * 16;
    int local[16];
    int s = 0;
    #pragma unroll
    for (int i = 0; i < 16; ++i) {
        int v = (base + i < N) ? counts[base + i] : 0;
        local[i] = v; s += v;
    }
    lsum[t] = s;
    __syncthreads();
    for (int d = 1; d < 1024; d <<= 1) {
        int v = 0;
        if (t >= d) v = lsum[t - d];
        __syncthreads();
        if (t >= d) lsum[t] += v;
        __syncthreads();
    }
    int run = (t ? lsum[t - 1] : 0);
    #pragma unroll
    for (int i = 0; i < 16; ++i) {
        if (base + i < N) { offs[base + i] = run; cursor[base + i] = run; }
        run += local[i];
    }
}

__global__ __launch_bounds__(256) void scatter_kernel(
    const int* __restrict__ ei, int* __restrict__ cursor,
    int* __restrict__ srcs, int E) {
    int e = blockIdx.x * 256 + threadIdx.x;
    if (e < E) {
        int d = ei[E + e];
        int p = atomicAdd(&cursor[d], 1);
        srcs[p] = ei[e];
    }
}

// ---------------- fused GAT: score + online softmax + aggregate ----------------
__global__ __launch_bounds__(256) void gat_fused_kernel(
    const ushort_t* __restrict__ cat, const int* __restrict__ srcs,
    const int* __restrict__ offs, const float* __restrict__ att,
    float* __restrict__ hgat, int E, int N) {
    int wid = (blockIdx.x * 256 + threadIdx.x) >> 6;
    int lane = threadIdx.x & 63;
    if (wid >= N) return;
    int d = wid;
    const uint4 rv = ((const uint4*)(cat + (size_t)d * NCAT + 512))[lane];
    float xr8[8];
    xr8[0] = bflo(rv.x); xr8[1] = bfhi(rv.x);
    xr8[2] = bflo(rv.y); xr8[3] = bfhi(rv.y);
    xr8[4] = bflo(rv.z); xr8[5] = bfhi(rv.z);
    xr8[6] = bflo(rv.w); xr8[7] = bfhi(rv.w);
    const float4 a0 = ((const float4*)att)[lane * 2];
    const float4 a1 = ((const float4*)att)[lane * 2 + 1];
    const float aw[8] = {a0.x, a0.y, a0.z, a0.w, a1.x, a1.y, a1.z, a1.w};
    float acc[8] = {};
    float dn = 0.f;

    auto process = [&](uint4 lv) {
        float xl8[8];
        xl8[0] = bflo(lv.x); xl8[1] = bfhi(lv.x);
        xl8[2] = bflo(lv.y); xl8[3] = bfhi(lv.y);
        xl8[4] = bflo(lv.z); xl8[5] = bfhi(lv.z);
        xl8[6] = bflo(lv.w); xl8[7] = bfhi(lv.w);
        float s = 0.f;
        #pragma unroll
        for (int j = 0; j < 8; ++j) {
            float v = xl8[j] + xr8[j];
            v = v > 0.f ? v : 0.2f * v;
            s = fmaf(v, aw[j], s);
        }
        #pragma unroll
        for (int off = 1; off < 16; off <<= 1) s += __shfl_xor(s, off);
        float ex = __expf(s);
        dn += ex;
        #pragma unroll
        for (int j = 0; j < 8; ++j) acc[j] = fmaf(ex, xl8[j], acc[j]);
    };

    process(((const uint4*)(cat + (size_t)d * NCAT))[lane]);

    int start = offs[d];
    int end = (d == N - 1) ? E : offs[d + 1];
    int p = start;
    for (; p + 1 < end; p += 2) {
        int s0 = srcs[p], s1 = srcs[p + 1];
        uint4 l0 = ((const uint4*)(cat + (size_t)s0 * NCAT))[lane];
        uint4 l1 = ((const uint4*)(cat + (size_t)s1 * NCAT))[lane];
        process(l0);
        process(l1);
    }
    if (p < end)
        process(((const uint4*)(cat + (size_t)srcs[p] * NCAT))[lane]);

    float inv = 1.f / dn;
    float v[8];
    #pragma unroll
    for (int j = 0; j < 8; ++j) {
        float t2 = acc[j] * inv;
        t2 += __shfl_xor(t2, 16);
        t2 += __shfl_xor(t2, 32);
        v[j] = t2;
    }
    int h = lane >> 4;
    int col = (lane & 15) * 8 + 2 * h;
    float2 outv = make_float2(0.25f * v[2 * h], 0.25f * v[2 * h + 1]);
    *(float2*)(hgat + (size_t)d * 128 + col) = outv;
}

// ---------------- layernorm epilogues ----------------
__global__ __launch_bounds__(256) void post_ln_kernel(
    float* __restrict__ buf, const float* __restrict__ bias,
    const float* __restrict__ gamma, const float* __restrict__ beta,
    float slope, int N) {
    int wid = (blockIdx.x * 256 + threadIdx.x) >> 6;
    int lane = threadIdx.x & 63;
    if (wid >= N) return;
    float* row = buf + (size_t)wid * 128;
    float v0 = row[lane], v1 = row[lane + 64];
    if (bias) { v0 += bias[lane]; v1 += bias[lane + 64]; }
    v0 = v0 > 0.f ? v0 : slope * v0;
    v1 = v1 > 0.f ? v1 : slope * v1;
    float s = v0 + v1;
    #pragma unroll
    for (int off = 32; off; off >>= 1) s += __shfl_xor(s, off);
    float mu = s * (1.f / 128.f);
    float d0 = v0 - mu, d1 = v1 - mu;
    float vs = d0 * d0 + d1 * d1;
    #pragma unroll
    for (int off = 32; off; off >>= 1) vs += __shfl_xor(vs, off);
    float inv = rsqrtf(vs * (1.f / 128.f) + 1e-5f);
    row[lane]      = d0 * inv * gamma[lane]      + beta[lane];
    row[lane + 64] = d1 * inv * gamma[lane + 64] + beta[lane + 64];
}

// out = LN(hgat + hc + res + res_b); res = cat[:, 1152:1280] bf16
__global__ __launch_bounds__(256) void fuse_ln_kernel(
    const float* __restrict__ a, const float* __restrict__ b2,
    const ushort_t* __restrict__ cat, const float* __restrict__ resb,
    const float* __restrict__ gamma, const float* __restrict__ beta,
    float* __restrict__ out, int N) {
    int wid = (blockIdx.x * 256 + threadIdx.x) >> 6;
    int lane = threadIdx.x & 63;
    if (wid >= N) return;
    size_t base = (size_t)wid * 128;
    size_t cbase = (size_t)wid * NCAT + 1152;
    float v0 = a[base + lane]      + b2[base + lane]
             + bf2f(cat[cbase + lane])      + resb[lane];
    float v1 = a[base + lane + 64] + b2[base + lane + 64]
             + bf2f(cat[cbase + lane + 64]) + resb[lane + 64];
    float s = v0 + v1;
    #pragma unroll
    for (int off = 32; off; off >>= 1) s += __shfl_xor(s, off);
    float mu = s * (1.f / 128.f);
    float d0 = v0 - mu, d1 = v1 - mu;
    float vs = d0 * d0 + d1 * d1;
    #pragma unroll
    for (int off = 32; off; off >>= 1) vs += __shfl_xor(vs, off);
    float inv = rsqrtf(vs * (1.f / 128.f) + 1e-5f);
    out[base + lane]      = d0 * inv * gamma[lane]      + beta[lane];
    out[base + lane + 64] = d1 * inv * gamma[lane + 64] + beta[lane + 64];
}

extern "C" void kernel_launch(void* const* d_in, const int* in_sizes, int n_in,
                              void* d_out, int out_size, void* d_ws, size_t ws_size,
                              hipStream_t stream) {
    const float* x         = (const float*)d_in[0];
    const int*   ei        = (const int*)d_in[1];
    const float* W_l       = (const float*)d_in[2];
    const float* W_r       = (const float*)d_in[3];
    const float* att       = (const float*)d_in[4];
    const float* gat_bias  = (const float*)d_in[5];
    const float* gat_gamma = (const float*)d_in[6];
    const float* gat_beta  = (const float*)d_in[7];
    const float* cnn_W     = (const float*)d_in[8];
    const float* cnn_b     = (const float*)d_in[9];
    const float* conv_W    = (const float*)d_in[10];
    const float* conv_b    = (const float*)d_in[11];
    const float* cnn_gamma = (const float*)d_in[12];
    const float* cnn_beta  = (const float*)d_in[13];
    const float* res_W     = (const float*)d_in[14];
    const float* res_b     = (const float*)d_in[15];
    const float* fuse_gamma= (const float*)d_in[16];
    const float* fuse_beta = (const float*)d_in[17];

    int N = in_sizes[0] / IN_F;   // 16384
    int E = in_sizes[1] / 2;      // 262144

    // workspace layout
    char* ws = (char*)d_ws;
    size_t off = 0;
    ushort_t* xb   = (ushort_t*)(ws + off); off += (size_t)N * IN_F * 2;     // 8MB
    ushort_t* Wt   = (ushort_t*)(ws + off); off += (size_t)NCAT * IN_F * 2;  // 0.65MB
    ushort_t* cat  = (ushort_t*)(ws + off); off += (size_t)N * NCAT * 2;     // 42MB
    int*  counts   = (int*)(ws + off);  off += (size_t)N * 4;
    int*  offs     = (int*)(ws + off);  off += (size_t)N * 4;
    int*  cursor   = (int*)(ws + off);  off += (size_t)N * 4;
    int*  srcs     = (int*)(ws + off);  off += (size_t)E * 4;                // 1MB
    float* hgat    = (float*)(ws + off); off += (size_t)N * 128 * 4;         // 8MB
    float* hc      = (float*)(ws + off); off += (size_t)N * 128 * 4;         // 8MB
    ushort_t* Wt2  = (ushort_t*)(ws + off); off += (size_t)7 * 128 * 128 * 2;

    hipMemsetAsync(counts, 0, (size_t)N * 4, stream);

    dim3 blk(256);
    // CSR build
    hist_kernel<<<(E + 255) / 256, blk, 0, stream>>>(ei, counts, E);
    scan_kernel<<<1, 1024, 0, stream>>>(counts, offs, cursor, N);
    scatter_kernel<<<(E + 255) / 256, blk, 0, stream>>>(ei, cursor, srcs, E);

    // operand prep
    cvt_x_kernel<<<(N * IN_F / 8 + 255) / 256, blk, 0, stream>>>(x, xb, N * IN_F);
    build_wt_kernel<<<(NCAT * 256 + 255) / 256, blk, 0, stream>>>(W_l, W_r, cnn_W, res_W, Wt);
    build_wt2_kernel<<<(7 * 128 * 128 + 255) / 256, blk, 0, stream>>>(conv_W, Wt2);

    // one fused MFMA GEMM for all four projections
    mfma_gemm<<<dim3(NCAT / 128, N / 128), blk, 0, stream>>>(xb, Wt, cat, N);

    // fused GAT (no atomics, online softmax)
    gat_fused_kernel<<<(N + 3) / 4, blk, 0, stream>>>(cat, srcs, offs, att, hgat, E, N);

    // MFMA conv branch
    conv_mfma<<<dim3(8, 32), blk, 0, stream>>>(cat, cnn_b, Wt2, hc);

    // epilogues
    post_ln_kernel<<<(N + 3) / 4, blk, 0, stream>>>(hgat, gat_bias, gat_gamma, gat_beta, 0.01f, N);
    post_ln_kernel<<<(N + 3) / 4, blk, 0, stream>>>(hc, conv_b, cnn_gamma, cnn_beta, 0.0f, N);
    fuse_ln_kernel<<<(N + 3) / 4, blk, 0, stream>>>(hgat, hc, cat, res_b, fuse_gamma, fuse_beta,
                                                    (float*)d_out, N);
}

// Round 6
// 160.243 us; speedup vs baseline: 4.4035x; 1.0975x over previous
//
#include <hip/hip_runtime.h>
#include <hip/hip_bf16.h>
#include <math.h>

#define IN_F 256
#define OUT_F 128
#define HEADS 4
#define HF 512    // HEADS*OUT_F
#define NCAT 1280 // 512 + 512 + 128 + 128

typedef __hip_bfloat16 bf16;
typedef unsigned short ushort_t;

using bf16x8 = __attribute__((ext_vector_type(8))) short;
using f32x4  = __attribute__((ext_vector_type(4))) float;

__device__ __forceinline__ float bflo(unsigned u) { return __uint_as_float(u << 16); }
__device__ __forceinline__ float bfhi(unsigned u) { return __uint_as_float(u & 0xffff0000u); }
__device__ __forceinline__ float bf2f(ushort_t u) { return __uint_as_float((unsigned)u << 16); }
__device__ __forceinline__ ushort_t f2bf(float f) {
    __hip_bfloat16 h = __float2bfloat16(f);
    return *reinterpret_cast<ushort_t*>(&h);
}

// sum over 16-lane row via DPP row_ror (all lanes end with full sum)
template <int CTRL>
__device__ __forceinline__ float dpp_add(float s) {
    int t = __builtin_amdgcn_update_dpp(0, __float_as_int(s), CTRL, 0xf, 0xf, true);
    return s + __int_as_float(t);
}
__device__ __forceinline__ float rowsum16(float s) {
    s = dpp_add<0x121>(s);  // ror:1
    s = dpp_add<0x122>(s);  // ror:2
    s = dpp_add<0x124>(s);  // ror:4
    s = dpp_add<0x128>(s);  // ror:8
    return s;
}

// ---------------- input conversions ----------------
__global__ __launch_bounds__(256) void cvt_x_kernel(
    const float* __restrict__ x, ushort_t* __restrict__ xb, int n) {
    int i = (blockIdx.x * 256 + threadIdx.x) * 8;
    if (i >= n) return;
    float4 a = *(const float4*)(x + i);
    float4 b = *(const float4*)(x + i + 4);
    uint4 o;
    o.x = f2bf(a.x) | ((unsigned)f2bf(a.y) << 16);
    o.y = f2bf(a.z) | ((unsigned)f2bf(a.w) << 16);
    o.z = f2bf(b.x) | ((unsigned)f2bf(b.y) << 16);
    o.w = f2bf(b.z) | ((unsigned)f2bf(b.w) << 16);
    *(uint4*)(xb + i) = o;
}

// merged weight prep: Wt[n][k] = concat(W)[k][n]; Wt2[k][o][i] = conv_W[o][i][k]
__global__ __launch_bounds__(256) void build_weights_kernel(
    const float* __restrict__ Wl, const float* __restrict__ Wr,
    const float* __restrict__ Wc, const float* __restrict__ Wres,
    const float* __restrict__ Wconv,
    ushort_t* __restrict__ Wt, ushort_t* __restrict__ Wt2) {
    int idx = blockIdx.x * 256 + threadIdx.x;
    if (idx < NCAT * 256) {
        int n = idx >> 8, k = idx & 255;
        float v;
        if (n < 512)       v = Wl[(size_t)k * 512 + n];
        else if (n < 1024) v = Wr[(size_t)k * 512 + (n - 512)];
        else if (n < 1152) v = Wc[(size_t)k * 128 + (n - 1024)];
        else               v = Wres[(size_t)k * 128 + (n - 1152)];
        Wt[idx] = f2bf(v);
    } else {
        int j = idx - NCAT * 256;
        if (j < 7 * 128 * 128) {
            int k = j >> 14, o = (j >> 7) & 127, i = j & 127;
            Wt2[j] = f2bf(Wconv[((size_t)o * 128 + i) * 7 + k]);
        }
    }
}

// ---------------- fused MFMA GEMM with split compact outputs ----------------
__global__ __launch_bounds__(256) void mfma_gemm(
    const ushort_t* __restrict__ A,   // [M][256] bf16
    const ushort_t* __restrict__ Wt,  // [1280][256] bf16
    ushort_t* __restrict__ xlb, ushort_t* __restrict__ xrb,
    ushort_t* __restrict__ xcb, ushort_t* __restrict__ resb,
    int M) {
    __shared__ ushort_t As[128][40];
    __shared__ ushort_t Bs[128][40];
    int tid = threadIdx.x;
    int lane = tid & 63, wid = tid >> 6;
    int wr = (wid >> 1) * 64, wc = (wid & 1) * 64;
    int brow = blockIdx.y * 128, bcol = blockIdx.x * 128;
    f32x4 acc[4][4] = {};
    int kb = (lane >> 4) * 8;
    int rl = lane & 15;
    for (int k0 = 0; k0 < 256; k0 += 32) {
        #pragma unroll
        for (int i = 0; i < 2; ++i) {
            int idx = tid + 256 * i;
            int row = idx >> 2, seg = idx & 3;
            *(uint4*)&As[row][seg * 8] =
                *(const uint4*)(A + (size_t)(brow + row) * 256 + k0 + seg * 8);
            *(uint4*)&Bs[row][seg * 8] =
                *(const uint4*)(Wt + (size_t)(bcol + row) * 256 + k0 + seg * 8);
        }
        __syncthreads();
        bf16x8 af[4], bfr[4];
        #pragma unroll
        for (int m = 0; m < 4; ++m) af[m] = *(const bf16x8*)&As[wr + m * 16 + rl][kb];
        #pragma unroll
        for (int n = 0; n < 4; ++n) bfr[n] = *(const bf16x8*)&Bs[wc + n * 16 + rl][kb];
        #pragma unroll
        for (int m = 0; m < 4; ++m)
            #pragma unroll
            for (int n = 0; n < 4; ++n)
                acc[m][n] = __builtin_amdgcn_mfma_f32_16x16x32_bf16(
                    af[m], bfr[n], acc[m][n], 0, 0, 0);
        __syncthreads();
    }
    // route this block's 128-col tile to its compact output buffer
    ushort_t* dstp; int cstride, cb;
    if (bcol < 512)       { dstp = xlb;  cstride = 512; cb = bcol; }
    else if (bcol < 1024) { dstp = xrb;  cstride = 512; cb = bcol - 512; }
    else if (bcol < 1152) { dstp = xcb;  cstride = 128; cb = bcol - 1024; }
    else                  { dstp = resb; cstride = 128; cb = bcol - 1152; }
    int rowb = (lane >> 4) * 4;
    #pragma unroll
    for (int m = 0; m < 4; ++m)
        #pragma unroll
        for (int n = 0; n < 4; ++n) {
            int col = cb + wc + n * 16 + rl;
            #pragma unroll
            for (int q = 0; q < 4; ++q) {
                int row = brow + wr + m * 16 + rowb + q;
                dstp[(size_t)row * cstride + col] = f2bf(acc[m][n][q]);
            }
        }
}

// ---------------- MFMA conv1d ----------------
__global__ __launch_bounds__(256) void conv_mfma(
    const ushort_t* __restrict__ xcb, const float* __restrict__ cnn_b,
    const ushort_t* __restrict__ Wt2, float* __restrict__ hc) {
    __shared__ ushort_t As[70][136];
    __shared__ ushort_t Bs[128][136];
    int tid = threadIdx.x;
    int lane = tid & 63, wid = tid >> 6;
    int wr = (wid >> 1) * 32, wc = (wid & 1) * 64;
    int b = blockIdx.y, l0 = blockIdx.x * 64;
    for (int u = tid; u < 70 * 16; u += 256) {
        int r = u >> 4, seg = u & 15;
        int l = l0 - 3 + r;
        uint4 o4 = make_uint4(0, 0, 0, 0);
        if (l >= 0 && l < 512) {
            uint4 v = *(const uint4*)(xcb + (size_t)(b * 512 + l) * 128 + seg * 8);
            float4 b0 = *(const float4*)(cnn_b + seg * 8);
            float4 b1 = *(const float4*)(cnn_b + seg * 8 + 4);
            o4.x = f2bf(bflo(v.x) + b0.x) | ((unsigned)f2bf(bfhi(v.x) + b0.y) << 16);
            o4.y = f2bf(bflo(v.y) + b0.z) | ((unsigned)f2bf(bfhi(v.y) + b0.w) << 16);
            o4.z = f2bf(bflo(v.z) + b1.x) | ((unsigned)f2bf(bfhi(v.z) + b1.y) << 16);
            o4.w = f2bf(bflo(v.w) + b1.z) | ((unsigned)f2bf(bfhi(v.w) + b1.w) << 16);
        }
        *(uint4*)&As[r][seg * 8] = o4;
    }
    f32x4 acc[2][4] = {};
    int rl = lane & 15, kb = (lane >> 4) * 8;
    for (int k = 0; k < 7; ++k) {
        __syncthreads();
        for (int u = tid; u < 128 * 16; u += 256) {
            int r = u >> 4, seg = u & 15;
            *(uint4*)&Bs[r][seg * 8] =
                *(const uint4*)(Wt2 + ((size_t)(k * 128 + r)) * 128 + seg * 8);
        }
        __syncthreads();
        #pragma unroll
        for (int kk = 0; kk < 4; ++kk) {
            bf16x8 af[2], bfr[4];
            af[0] = *(const bf16x8*)&As[wr + 0  + rl + k][kk * 32 + kb];
            af[1] = *(const bf16x8*)&As[wr + 16 + rl + k][kk * 32 + kb];
            #pragma unroll
            for (int n = 0; n < 4; ++n)
                bfr[n] = *(const bf16x8*)&Bs[wc + n * 16 + rl][kk * 32 + kb];
            #pragma unroll
            for (int m = 0; m < 2; ++m)
                #pragma unroll
                for (int n = 0; n < 4; ++n)
                    acc[m][n] = __builtin_amdgcn_mfma_f32_16x16x32_bf16(
                        af[m], bfr[n], acc[m][n], 0, 0, 0);
        }
    }
    int rowb = (lane >> 4) * 4;
    #pragma unroll
    for (int m = 0; m < 2; ++m)
        #pragma unroll
        for (int n = 0; n < 4; ++n) {
            int col = wc + n * 16 + rl;
            #pragma unroll
            for (int q = 0; q < 4; ++q) {
                int l = l0 + wr + m * 16 + rowb + q;
                hc[(size_t)(b * 512 + l) * 128 + col] = acc[m][n][q];
            }
        }
}

// ---------------- CSR build ----------------
__global__ __launch_bounds__(256) void hist_kernel(
    const int* __restrict__ ei, int* __restrict__ counts, int E) {
    int e = blockIdx.x * 256 + threadIdx.x;
    if (e < E) atomicAdd(&counts[ei[E + e]], 1);
}

// 1024 threads x 16 elems; wave-scan based (2 barriers)
__global__ __launch_bounds__(1024) void scan_kernel(
    const int* __restrict__ counts, int* __restrict__ offs,
    int* __restrict__ cursor, int N) {
    __shared__ int wsum[16];
    int t = threadIdx.x;
    int lane = t & 63, w = t >> 6;
    int base = t * 16;
    int local[16], s = 0;
    #pragma unroll
    for (int i = 0; i < 16; ++i) {
        int v = (base + i < N) ? counts[base + i] : 0;
        local[i] = v; s += v;
    }
    int sc = s;   // inclusive wave scan
    #pragma unroll
    for (int off = 1; off < 64; off <<= 1) {
        int v = __shfl_up(sc, off);
        if (lane >= off) sc += v;
    }
    if (lane == 63) wsum[w] = sc;
    __syncthreads();
    if (w == 0 && lane < 16) {
        int v = wsum[lane];
        int scv = v;
        #pragma unroll
        for (int off = 1; off < 16; off <<= 1) {
            int u = __shfl_up(scv, off);
            if (lane >= off) scv += u;
        }
        wsum[lane] = scv - v;  // exclusive
    }
    __syncthreads();
    int run = wsum[w] + sc - s;
    #pragma unroll
    for (int i = 0; i < 16; ++i) {
        if (base + i < N) { offs[base + i] = run; cursor[base + i] = run; }
        run += local[i];
    }
}

__global__ __launch_bounds__(256) void scatter_kernel(
    const int* __restrict__ ei, int* __restrict__ cursor,
    int* __restrict__ srcs, int E) {
    int e = blockIdx.x * 256 + threadIdx.x;
    if (e < E) {
        int d = ei[E + e];
        int p = atomicAdd(&cursor[d], 1);
        srcs[p] = ei[e];
    }
}

// ---------------- fused GAT: score + softmax + aggregate + bias/leaky/LN ----------------
__global__ __launch_bounds__(256) void gat_fused_kernel(
    const ushort_t* __restrict__ xlb, const ushort_t* __restrict__ xrb,
    const int* __restrict__ srcs, const int* __restrict__ offs,
    const float* __restrict__ att, const float* __restrict__ gat_bias,
    const float* __restrict__ gat_gamma, const float* __restrict__ gat_beta,
    float* __restrict__ hgat_ln, int E, int N) {
    int wid = (blockIdx.x * 256 + threadIdx.x) >> 6;
    int lane = threadIdx.x & 63;
    if (wid >= N) return;
    int d = wid;
    const uint4 rv = ((const uint4*)(xrb + (size_t)d * HF))[lane];
    float xr8[8];
    xr8[0] = bflo(rv.x); xr8[1] = bfhi(rv.x);
    xr8[2] = bflo(rv.y); xr8[3] = bfhi(rv.y);
    xr8[4] = bflo(rv.z); xr8[5] = bfhi(rv.z);
    xr8[6] = bflo(rv.w); xr8[7] = bfhi(rv.w);
    const float4 a0 = ((const float4*)att)[lane * 2];
    const float4 a1 = ((const float4*)att)[lane * 2 + 1];
    const float aw[8] = {a0.x, a0.y, a0.z, a0.w, a1.x, a1.y, a1.z, a1.w};
    float acc[8] = {};
    float dn = 0.f;

    auto process = [&](uint4 lv) {
        float xl8[8];
        xl8[0] = bflo(lv.x); xl8[1] = bfhi(lv.x);
        xl8[2] = bflo(lv.y); xl8[3] = bfhi(lv.y);
        xl8[4] = bflo(lv.z); xl8[5] = bfhi(lv.z);
        xl8[6] = bflo(lv.w); xl8[7] = bfhi(lv.w);
        float s = 0.f;
        #pragma unroll
        for (int j = 0; j < 8; ++j) {
            float v = xl8[j] + xr8[j];
            v = v > 0.f ? v : 0.2f * v;
            s = fmaf(v, aw[j], s);
        }
        s = rowsum16(s);              // DPP row reduce, VALU-speed
        float ex = __expf(s);
        dn += ex;
        #pragma unroll
        for (int j = 0; j < 8; ++j) acc[j] = fmaf(ex, xl8[j], acc[j]);
    };

    process(((const uint4*)(xlb + (size_t)d * HF))[lane]);   // self-loop

    int start = offs[d];
    int end = (d == N - 1) ? E : offs[d + 1];
    int p = start;
    for (; p + 3 < end; p += 4) {   // 4-wide gather batches (static regs)
        int s0 = srcs[p], s1 = srcs[p + 1], s2 = srcs[p + 2], s3 = srcs[p + 3];
        uint4 l0 = ((const uint4*)(xlb + (size_t)s0 * HF))[lane];
        uint4 l1 = ((const uint4*)(xlb + (size_t)s1 * HF))[lane];
        uint4 l2 = ((const uint4*)(xlb + (size_t)s2 * HF))[lane];
        uint4 l3 = ((const uint4*)(xlb + (size_t)s3 * HF))[lane];
        process(l0); process(l1); process(l2); process(l3);
    }
    for (; p < end; ++p)
        process(((const uint4*)(xlb + (size_t)srcs[p] * HF))[lane]);

    float inv = 1.f / dn;
    float v[8];
    #pragma unroll
    for (int j = 0; j < 8; ++j) {
        float t2 = acc[j] * inv;
        t2 += __shfl_xor(t2, 16);
        t2 += __shfl_xor(t2, 32);
        v[j] = t2;
    }
    // epilogue: + gat_bias, leaky 0.01, LayerNorm — row lives in this wave (2 cols/lane)
    int h = lane >> 4;
    int col = (lane & 15) * 8 + 2 * h;
    float g0 = 0.25f * v[2 * h]     + gat_bias[col];
    float g1 = 0.25f * v[2 * h + 1] + gat_bias[col + 1];
    g0 = g0 > 0.f ? g0 : 0.01f * g0;
    g1 = g1 > 0.f ? g1 : 0.01f * g1;
    float s = g0 + g1;
    #pragma unroll
    for (int off = 32; off; off >>= 1) s += __shfl_xor(s, off);
    float mu = s * (1.f / 128.f);
    float d0 = g0 - mu, d1 = g1 - mu;
    float vs = d0 * d0 + d1 * d1;
    #pragma unroll
    for (int off = 32; off; off >>= 1) vs += __shfl_xor(vs, off);
    float rinv = rsqrtf(vs * (1.f / 128.f) + 1e-5f);
    hgat_ln[(size_t)d * 128 + col]     = d0 * rinv * gat_gamma[col]     + gat_beta[col];
    hgat_ln[(size_t)d * 128 + col + 1] = d1 * rinv * gat_gamma[col + 1] + gat_beta[col + 1];
}

// ---------------- final epilogue: LN(hc) inline + fuse + LN ----------------
__global__ __launch_bounds__(256) void final_ln_kernel(
    const float* __restrict__ hgat_ln, const float* __restrict__ hc,
    const ushort_t* __restrict__ resb, const float* __restrict__ conv_b,
    const float* __restrict__ cnn_gamma, const float* __restrict__ cnn_beta,
    const float* __restrict__ res_b, const float* __restrict__ fuse_gamma,
    const float* __restrict__ fuse_beta, float* __restrict__ out, int N) {
    int wid = (blockIdx.x * 256 + threadIdx.x) >> 6;
    int lane = threadIdx.x & 63;
    if (wid >= N) return;
    size_t base = (size_t)wid * 128;
    // hc: + conv_b, relu, LN(cnn)
    float h0 = fmaxf(hc[base + lane]      + conv_b[lane], 0.f);
    float h1 = fmaxf(hc[base + lane + 64] + conv_b[lane + 64], 0.f);
    float s = h0 + h1;
    #pragma unroll
    for (int off = 32; off; off >>= 1) s += __shfl_xor(s, off);
    float mu = s * (1.f / 128.f);
    float d0 = h0 - mu, d1 = h1 - mu;
    float vs = d0 * d0 + d1 * d1;
    #pragma unroll
    for (int off = 32; off; off >>= 1) vs += __shfl_xor(vs, off);
    float inv = rsqrtf(vs * (1.f / 128.f) + 1e-5f);
    float hcn0 = d0 * inv * cnn_gamma[lane]      + cnn_beta[lane];
    float hcn1 = d1 * inv * cnn_gamma[lane + 64] + cnn_beta[lane + 64];
    // fuse: hgat_ln + hcn + res + res_b, then LN(fuse)
    float v0 = hgat_ln[base + lane]      + hcn0
             + bf2f(resb[base + lane])      + res_b[lane];
    float v1 = hgat_ln[base + lane + 64] + hcn1
             + bf2f(resb[base + lane + 64]) + res_b[lane + 64];
    s = v0 + v1;
    #pragma unroll
    for (int off = 32; off; off >>= 1) s += __shfl_xor(s, off);
    mu = s * (1.f / 128.f);
    d0 = v0 - mu; d1 = v1 - mu;
    vs = d0 * d0 + d1 * d1;
    #pragma unroll
    for (int off = 32; off; off >>= 1) vs += __shfl_xor(vs, off);
    inv = rsqrtf(vs * (1.f / 128.f) + 1e-5f);
    out[base + lane]      = d0 * inv * fuse_gamma[lane]      + fuse_beta[lane];
    out[base + lane + 64] = d1 * inv * fuse_gamma[lane + 64] + fuse_beta[lane + 64];
}

extern "C" void kernel_launch(void* const* d_in, const int* in_sizes, int n_in,
                              void* d_out, int out_size, void* d_ws, size_t ws_size,
                              hipStream_t stream) {
    const float* x         = (const float*)d_in[0];
    const int*   ei        = (const int*)d_in[1];
    const float* W_l       = (const float*)d_in[2];
    const float* W_r       = (const float*)d_in[3];
    const float* att       = (const float*)d_in[4];
    const float* gat_bias  = (const float*)d_in[5];
    const float* gat_gamma = (const float*)d_in[6];
    const float* gat_beta  = (const float*)d_in[7];
    const float* cnn_W     = (const float*)d_in[8];
    const float* cnn_b     = (const float*)d_in[9];
    const float* conv_W    = (const float*)d_in[10];
    const float* conv_b    = (const float*)d_in[11];
    const float* cnn_gamma = (const float*)d_in[12];
    const float* cnn_beta  = (const float*)d_in[13];
    const float* res_W     = (const float*)d_in[14];
    const float* res_b     = (const float*)d_in[15];
    const float* fuse_gamma= (const float*)d_in[16];
    const float* fuse_beta = (const float*)d_in[17];

    int N = in_sizes[0] / IN_F;   // 16384
    int E = in_sizes[1] / 2;      // 262144

    // workspace layout
    char* ws = (char*)d_ws;
    size_t off = 0;
    ushort_t* xb     = (ushort_t*)(ws + off); off += (size_t)N * IN_F * 2;    // 8MB
    ushort_t* Wt     = (ushort_t*)(ws + off); off += (size_t)NCAT * IN_F * 2; // 0.65MB
    ushort_t* Wt2    = (ushort_t*)(ws + off); off += (size_t)7 * 128 * 128 * 2;
    ushort_t* xlb    = (ushort_t*)(ws + off); off += (size_t)N * HF * 2;      // 16MB
    ushort_t* xrb    = (ushort_t*)(ws + off); off += (size_t)N * HF * 2;      // 16MB
    ushort_t* xcb    = (ushort_t*)(ws + off); off += (size_t)N * 128 * 2;     // 4MB
    ushort_t* resb   = (ushort_t*)(ws + off); off += (size_t)N * 128 * 2;     // 4MB
    int*  counts     = (int*)(ws + off);  off += (size_t)N * 4;
    int*  offs       = (int*)(ws + off);  off += (size_t)N * 4;
    int*  cursor     = (int*)(ws + off);  off += (size_t)N * 4;
    int*  srcs       = (int*)(ws + off);  off += (size_t)E * 4;               // 1MB
    float* hgat_ln   = (float*)(ws + off); off += (size_t)N * 128 * 4;        // 8MB
    float* hc        = (float*)(ws + off); off += (size_t)N * 128 * 4;        // 8MB

    hipMemsetAsync(counts, 0, (size_t)N * 4, stream);

    dim3 blk(256);
    // CSR build
    hist_kernel<<<(E + 255) / 256, blk, 0, stream>>>(ei, counts, E);
    scan_kernel<<<1, 1024, 0, stream>>>(counts, offs, cursor, N);
    scatter_kernel<<<(E + 255) / 256, blk, 0, stream>>>(ei, cursor, srcs, E);

    // operand prep
    cvt_x_kernel<<<(N * IN_F / 8 + 255) / 256, blk, 0, stream>>>(x, xb, N * IN_F);
    build_weights_kernel<<<(NCAT * 256 + 7 * 128 * 128 + 255) / 256, blk, 0, stream>>>(
        W_l, W_r, cnn_W, res_W, conv_W, Wt, Wt2);

    // one MFMA GEMM for all four projections, split compact outputs
    mfma_gemm<<<dim3(NCAT / 128, N / 128), blk, 0, stream>>>(
        xb, Wt, xlb, xrb, xcb, resb, N);

    // fused GAT (gather from compact 16MB table; LN fused in epilogue)
    gat_fused_kernel<<<(N + 3) / 4, blk, 0, stream>>>(
        xlb, xrb, srcs, offs, att, gat_bias, gat_gamma, gat_beta, hgat_ln, E, N);

    // MFMA conv branch
    conv_mfma<<<dim3(8, 32), blk, 0, stream>>>(xcb, cnn_b, Wt2, hc);

    // single fused epilogue
    final_ln_kernel<<<(N + 3) / 4, blk, 0, stream>>>(
        hgat_ln, hc, resb, conv_b, cnn_gamma, cnn_beta, res_b,
        fuse_gamma, fuse_beta, (float*)d_out, N);
}

// Round 7
// 150.813 us; speedup vs baseline: 4.6788x; 1.0625x over previous
//
#include <hip/hip_runtime.h>
#include <hip/hip_bf16.h>
#include <math.h>

#define IN_F 256
#define OUT_F 128
#define HEADS 4
#define HF 512    // HEADS*OUT_F
#define NCAT 1280 // 512 + 512 + 128 + 128

typedef __hip_bfloat16 bf16;
typedef unsigned short ushort_t;

using bf16x8 = __attribute__((ext_vector_type(8))) short;
using f32x4  = __attribute__((ext_vector_type(4))) float;

__device__ __forceinline__ float bflo(unsigned u) { return __uint_as_float(u << 16); }
__device__ __forceinline__ float bfhi(unsigned u) { return __uint_as_float(u & 0xffff0000u); }
__device__ __forceinline__ float bf2f(ushort_t u) { return __uint_as_float((unsigned)u << 16); }
__device__ __forceinline__ ushort_t f2bf(float f) {
    __hip_bfloat16 h = __float2bfloat16(f);
    return *reinterpret_cast<ushort_t*>(&h);
}

// sum over 16-lane row via DPP row_ror (all lanes end with full sum)
template <int CTRL>
__device__ __forceinline__ float dpp_add(float s) {
    int t = __builtin_amdgcn_update_dpp(0, __float_as_int(s), CTRL, 0xf, 0xf, true);
    return s + __int_as_float(t);
}
__device__ __forceinline__ float rowsum16(float s) {
    s = dpp_add<0x121>(s);
    s = dpp_add<0x122>(s);
    s = dpp_add<0x124>(s);
    s = dpp_add<0x128>(s);
    return s;
}

// ---------------- fused prep: cvt_x | build weights | hist ----------------
__global__ __launch_bounds__(256) void prep_kernel(
    const float* __restrict__ x, ushort_t* __restrict__ xb, int n_cvt,
    const float* __restrict__ Wl, const float* __restrict__ Wr,
    const float* __restrict__ Wc, const float* __restrict__ Wres,
    const float* __restrict__ Wconv,
    ushort_t* __restrict__ Wt, ushort_t* __restrict__ Wt2,
    const int* __restrict__ ei, int* __restrict__ counts, int E,
    int g1, int g2) {
    int b = blockIdx.x;
    if (b < g1) {
        int i = (b * 256 + threadIdx.x) * 8;
        if (i >= n_cvt) return;
        float4 a = *(const float4*)(x + i);
        float4 c = *(const float4*)(x + i + 4);
        uint4 o;
        o.x = f2bf(a.x) | ((unsigned)f2bf(a.y) << 16);
        o.y = f2bf(a.z) | ((unsigned)f2bf(a.w) << 16);
        o.z = f2bf(c.x) | ((unsigned)f2bf(c.y) << 16);
        o.w = f2bf(c.z) | ((unsigned)f2bf(c.w) << 16);
        *(uint4*)(xb + i) = o;
    } else if (b < g2) {
        int idx = (b - g1) * 256 + threadIdx.x;
        if (idx < NCAT * 256) {
            int n = idx >> 8, k = idx & 255;
            float v;
            if (n < 512)       v = Wl[(size_t)k * 512 + n];
            else if (n < 1024) v = Wr[(size_t)k * 512 + (n - 512)];
            else if (n < 1152) v = Wc[(size_t)k * 128 + (n - 1024)];
            else               v = Wres[(size_t)k * 128 + (n - 1152)];
            Wt[idx] = f2bf(v);
        } else {
            int j = idx - NCAT * 256;
            if (j < 7 * 128 * 128) {
                int k = j >> 14, o = (j >> 7) & 127, i = j & 127;
                Wt2[j] = f2bf(Wconv[((size_t)o * 128 + i) * 7 + k]);
            }
        }
    } else {
        int e = (b - g2) * 256 + threadIdx.x;
        if (e < E) atomicAdd(&counts[ei[E + e]], 1);
    }
}

// ---------------- fused MFMA GEMM with split compact outputs ----------------
__global__ __launch_bounds__(256) void mfma_gemm(
    const ushort_t* __restrict__ A,   // [M][256] bf16
    const ushort_t* __restrict__ Wt,  // [1280][256] bf16
    ushort_t* __restrict__ xlb, ushort_t* __restrict__ xrb,
    ushort_t* __restrict__ xcb, ushort_t* __restrict__ resb,
    int M) {
    __shared__ ushort_t As[128][40];
    __shared__ ushort_t Bs[128][40];
    int tid = threadIdx.x;
    int lane = tid & 63, wid = tid >> 6;
    int wr = (wid >> 1) * 64, wc = (wid & 1) * 64;
    int brow = blockIdx.y * 128, bcol = blockIdx.x * 128;
    f32x4 acc[4][4] = {};
    int kb = (lane >> 4) * 8;
    int rl = lane & 15;
    for (int k0 = 0; k0 < 256; k0 += 32) {
        #pragma unroll
        for (int i = 0; i < 2; ++i) {
            int idx = tid + 256 * i;
            int row = idx >> 2, seg = idx & 3;
            *(uint4*)&As[row][seg * 8] =
                *(const uint4*)(A + (size_t)(brow + row) * 256 + k0 + seg * 8);
            *(uint4*)&Bs[row][seg * 8] =
                *(const uint4*)(Wt + (size_t)(bcol + row) * 256 + k0 + seg * 8);
        }
        __syncthreads();
        bf16x8 af[4], bfr[4];
        #pragma unroll
        for (int m = 0; m < 4; ++m) af[m] = *(const bf16x8*)&As[wr + m * 16 + rl][kb];
        #pragma unroll
        for (int n = 0; n < 4; ++n) bfr[n] = *(const bf16x8*)&Bs[wc + n * 16 + rl][kb];
        #pragma unroll
        for (int m = 0; m < 4; ++m)
            #pragma unroll
            for (int n = 0; n < 4; ++n)
                acc[m][n] = __builtin_amdgcn_mfma_f32_16x16x32_bf16(
                    af[m], bfr[n], acc[m][n], 0, 0, 0);
        __syncthreads();
    }
    ushort_t* dstp; int cstride, cb;
    if (bcol < 512)       { dstp = xlb;  cstride = 512; cb = bcol; }
    else if (bcol < 1024) { dstp = xrb;  cstride = 512; cb = bcol - 512; }
    else if (bcol < 1152) { dstp = xcb;  cstride = 128; cb = bcol - 1024; }
    else                  { dstp = resb; cstride = 128; cb = bcol - 1152; }
    int rowb = (lane >> 4) * 4;
    #pragma unroll
    for (int m = 0; m < 4; ++m)
        #pragma unroll
        for (int n = 0; n < 4; ++n) {
            int col = cb + wc + n * 16 + rl;
            #pragma unroll
            for (int q = 0; q < 4; ++q) {
                int row = brow + wr + m * 16 + rowb + q;
                dstp[(size_t)row * cstride + col] = f2bf(acc[m][n][q]);
            }
        }
}

// ---------------- CSR build ----------------
__global__ __launch_bounds__(1024) void scan_kernel(
    const int* __restrict__ counts, int* __restrict__ offs,
    int* __restrict__ cursor, int N) {
    __shared__ int wsum[16];
    int t = threadIdx.x;
    int lane = t & 63, w = t >> 6;
    int base = t * 16;
    int local[16], s = 0;
    #pragma unroll
    for (int i = 0; i < 16; ++i) {
        int v = (base + i < N) ? counts[base + i] : 0;
        local[i] = v; s += v;
    }
    int sc = s;
    #pragma unroll
    for (int off = 1; off < 64; off <<= 1) {
        int v = __shfl_up(sc, off);
        if (lane >= off) sc += v;
    }
    if (lane == 63) wsum[w] = sc;
    __syncthreads();
    if (w == 0 && lane < 16) {
        int v = wsum[lane];
        int scv = v;
        #pragma unroll
        for (int off = 1; off < 16; off <<= 1) {
            int u = __shfl_up(scv, off);
            if (lane >= off) scv += u;
        }
        wsum[lane] = scv - v;
    }
    __syncthreads();
    int run = wsum[w] + sc - s;
    #pragma unroll
    for (int i = 0; i < 16; ++i) {
        if (base + i < N) { offs[base + i] = run; cursor[base + i] = run; }
        run += local[i];
    }
}

__global__ __launch_bounds__(256) void scatter_kernel(
    const int* __restrict__ ei, int* __restrict__ cursor,
    int* __restrict__ srcs, int E) {
    int e = blockIdx.x * 256 + threadIdx.x;
    if (e < E) {
        int d = ei[E + e];
        int p = atomicAdd(&cursor[d], 1);
        srcs[p] = ei[e];
    }
}

// ---------------- fused GAT: score + softmax + aggregate + bias/leaky/LN ----------------
__global__ __launch_bounds__(256) void gat_fused_kernel(
    const ushort_t* __restrict__ xlb, const ushort_t* __restrict__ xrb,
    const int* __restrict__ srcs, const int* __restrict__ offs,
    const float* __restrict__ att, const float* __restrict__ gat_bias,
    const float* __restrict__ gat_gamma, const float* __restrict__ gat_beta,
    float* __restrict__ hgat_ln, int E, int N) {
    int wid = (blockIdx.x * 256 + threadIdx.x) >> 6;
    int lane = threadIdx.x & 63;
    if (wid >= N) return;
    int d = wid;
    const uint4 rv = ((const uint4*)(xrb + (size_t)d * HF))[lane];
    float xr8[8];
    xr8[0] = bflo(rv.x); xr8[1] = bfhi(rv.x);
    xr8[2] = bflo(rv.y); xr8[3] = bfhi(rv.y);
    xr8[4] = bflo(rv.z); xr8[5] = bfhi(rv.z);
    xr8[6] = bflo(rv.w); xr8[7] = bfhi(rv.w);
    const float4 a0 = ((const float4*)att)[lane * 2];
    const float4 a1 = ((const float4*)att)[lane * 2 + 1];
    const float aw[8] = {a0.x, a0.y, a0.z, a0.w, a1.x, a1.y, a1.z, a1.w};
    float acc[8] = {};
    float dn = 0.f;

    // leaky0.2(v) = 0.6v + 0.4|v|  (abs is a free src modifier)
    auto process = [&](uint4 lv) {
        float xl8[8];
        xl8[0] = bflo(lv.x); xl8[1] = bfhi(lv.x);
        xl8[2] = bflo(lv.y); xl8[3] = bfhi(lv.y);
        xl8[4] = bflo(lv.z); xl8[5] = bfhi(lv.z);
        xl8[6] = bflo(lv.w); xl8[7] = bfhi(lv.w);
        float s1 = 0.f, s2 = 0.f;
        #pragma unroll
        for (int j = 0; j < 8; ++j) {
            float v = xl8[j] + xr8[j];
            s1 = fmaf(v, aw[j], s1);
            s2 = fmaf(fabsf(v), aw[j], s2);
        }
        float s = fmaf(0.6f, s1, 0.4f * s2);
        s = rowsum16(s);
        float ex = __expf(s);
        dn += ex;
        #pragma unroll
        for (int j = 0; j < 8; ++j) acc[j] = fmaf(ex, xl8[j], acc[j]);
    };

    process(((const uint4*)(xlb + (size_t)d * HF))[lane]);   // self-loop

    int start = offs[d];
    int end = (d == N - 1) ? E : offs[d + 1];
    int p = start;
    for (; p + 3 < end; p += 4) {
        int s0 = srcs[p], s1 = srcs[p + 1], s2 = srcs[p + 2], s3 = srcs[p + 3];
        uint4 l0 = ((const uint4*)(xlb + (size_t)s0 * HF))[lane];
        uint4 l1 = ((const uint4*)(xlb + (size_t)s1 * HF))[lane];
        uint4 l2 = ((const uint4*)(xlb + (size_t)s2 * HF))[lane];
        uint4 l3 = ((const uint4*)(xlb + (size_t)s3 * HF))[lane];
        process(l0); process(l1); process(l2); process(l3);
    }
    for (; p < end; ++p)
        process(((const uint4*)(xlb + (size_t)srcs[p] * HF))[lane]);

    float inv = 1.f / dn;
    float v[8];
    #pragma unroll
    for (int j = 0; j < 8; ++j) {
        float t2 = acc[j] * inv;
        t2 += __shfl_xor(t2, 16);
        t2 += __shfl_xor(t2, 32);
        v[j] = t2;
    }
    int h = lane >> 4;
    int col = (lane & 15) * 8 + 2 * h;
    float g0 = 0.25f * v[2 * h]     + gat_bias[col];
    float g1 = 0.25f * v[2 * h + 1] + gat_bias[col + 1];
    g0 = g0 > 0.f ? g0 : 0.01f * g0;
    g1 = g1 > 0.f ? g1 : 0.01f * g1;
    float s = g0 + g1;
    #pragma unroll
    for (int off = 32; off; off >>= 1) s += __shfl_xor(s, off);
    float mu = s * (1.f / 128.f);
    float d0 = g0 - mu, d1 = g1 - mu;
    float vs = d0 * d0 + d1 * d1;
    #pragma unroll
    for (int off = 32; off; off >>= 1) vs += __shfl_xor(vs, off);
    float rinv = rsqrtf(vs * (1.f / 128.f) + 1e-5f);
    hgat_ln[(size_t)d * 128 + col]     = d0 * rinv * gat_gamma[col]     + gat_beta[col];
    hgat_ln[(size_t)d * 128 + col + 1] = d1 * rinv * gat_gamma[col + 1] + gat_beta[col + 1];
}

// ---------------- MFMA conv1d + relu + LN(cnn) + fuse + LN -> out ----------------
// grid (16 L-tiles of 32, 32 batches) = 512 blocks; 4 waves (2 row x 2 col)
__global__ __launch_bounds__(256) void conv_fuse_kernel(
    const ushort_t* __restrict__ xcb, const float* __restrict__ cnn_b,
    const ushort_t* __restrict__ Wt2,
    const float* __restrict__ hgat_ln, const ushort_t* __restrict__ resb,
    const float* __restrict__ conv_b,
    const float* __restrict__ cnn_gamma, const float* __restrict__ cnn_beta,
    const float* __restrict__ res_b,
    const float* __restrict__ fuse_gamma, const float* __restrict__ fuse_beta,
    float* __restrict__ out) {
    __shared__ ushort_t As[38][136];   // rows l0-3 .. l0+34
    __shared__ ushort_t Bs[128][136];
    __shared__ float hbuf[32][129];
    int tid = threadIdx.x;
    int lane = tid & 63, wid = tid >> 6;
    int wr = (wid >> 1) * 16, wc = (wid & 1) * 64;
    int b = blockIdx.y, l0 = blockIdx.x * 32;
    for (int u = tid; u < 38 * 16; u += 256) {
        int r = u >> 4, seg = u & 15;
        int l = l0 - 3 + r;
        uint4 o4 = make_uint4(0, 0, 0, 0);
        if (l >= 0 && l < 512) {
            uint4 v = *(const uint4*)(xcb + (size_t)(b * 512 + l) * 128 + seg * 8);
            float4 b0 = *(const float4*)(cnn_b + seg * 8);
            float4 b1 = *(const float4*)(cnn_b + seg * 8 + 4);
            o4.x = f2bf(bflo(v.x) + b0.x) | ((unsigned)f2bf(bfhi(v.x) + b0.y) << 16);
            o4.y = f2bf(bflo(v.y) + b0.z) | ((unsigned)f2bf(bfhi(v.y) + b0.w) << 16);
            o4.z = f2bf(bflo(v.z) + b1.x) | ((unsigned)f2bf(bfhi(v.z) + b1.y) << 16);
            o4.w = f2bf(bflo(v.w) + b1.z) | ((unsigned)f2bf(bfhi(v.w) + b1.w) << 16);
        }
        *(uint4*)&As[r][seg * 8] = o4;
    }
    f32x4 acc[4] = {};
    int rl = lane & 15, kb = (lane >> 4) * 8;
    for (int k = 0; k < 7; ++k) {
        __syncthreads();
        for (int u = tid; u < 128 * 16; u += 256) {
            int r = u >> 4, seg = u & 15;
            *(uint4*)&Bs[r][seg * 8] =
                *(const uint4*)(Wt2 + ((size_t)(k * 128 + r)) * 128 + seg * 8);
        }
        __syncthreads();
        #pragma unroll
        for (int kk = 0; kk < 4; ++kk) {
            bf16x8 af = *(const bf16x8*)&As[wr + rl + k][kk * 32 + kb];
            #pragma unroll
            for (int n = 0; n < 4; ++n) {
                bf16x8 bfr = *(const bf16x8*)&Bs[wc + n * 16 + rl][kk * 32 + kb];
                acc[n] = __builtin_amdgcn_mfma_f32_16x16x32_bf16(af, bfr, acc[n], 0, 0, 0);
            }
        }
    }
    __syncthreads();   // done with As/Bs; hbuf phase
    int rowb = (lane >> 4) * 4;
    #pragma unroll
    for (int n = 0; n < 4; ++n) {
        int col = wc + n * 16 + rl;
        float cb = conv_b[col];
        #pragma unroll
        for (int q = 0; q < 4; ++q) {
            int r = wr + rowb + q;
            hbuf[r][col] = fmaxf(acc[n][q] + cb, 0.f);
        }
    }
    __syncthreads();
    // LN(cnn) + fuse + LN(fuse): 8 rows per wave, 2 cols per lane
    for (int r = wid * 8; r < wid * 8 + 8; ++r) {
        int grow = b * 512 + l0 + r;
        float h0 = hbuf[r][lane], h1 = hbuf[r][lane + 64];
        float s = h0 + h1;
        #pragma unroll
        for (int off = 32; off; off >>= 1) s += __shfl_xor(s, off);
        float mu = s * (1.f / 128.f);
        float d0 = h0 - mu, d1 = h1 - mu;
        float vs = d0 * d0 + d1 * d1;
        #pragma unroll
        for (int off = 32; off; off >>= 1) vs += __shfl_xor(vs, off);
        float inv = rsqrtf(vs * (1.f / 128.f) + 1e-5f);
        float hcn0 = d0 * inv * cnn_gamma[lane]      + cnn_beta[lane];
        float hcn1 = d1 * inv * cnn_gamma[lane + 64] + cnn_beta[lane + 64];
        size_t base = (size_t)grow * 128;
        float v0 = hgat_ln[base + lane]      + hcn0
                 + bf2f(resb[base + lane])      + res_b[lane];
        float v1 = hgat_ln[base + lane + 64] + hcn1
                 + bf2f(resb[base + lane + 64]) + res_b[lane + 64];
        s = v0 + v1;
        #pragma unroll
        for (int off = 32; off; off >>= 1) s += __shfl_xor(s, off);
        mu = s * (1.f / 128.f);
        d0 = v0 - mu; d1 = v1 - mu;
        vs = d0 * d0 + d1 * d1;
        #pragma unroll
        for (int off = 32; off; off >>= 1) vs += __shfl_xor(vs, off);
        inv = rsqrtf(vs * (1.f / 128.f) + 1e-5f);
        out[base + lane]      = d0 * inv * fuse_gamma[lane]      + fuse_beta[lane];
        out[base + lane + 64] = d1 * inv * fuse_gamma[lane + 64] + fuse_beta[lane + 64];
    }
}

extern "C" void kernel_launch(void* const* d_in, const int* in_sizes, int n_in,
                              void* d_out, int out_size, void* d_ws, size_t ws_size,
                              hipStream_t stream) {
    const float* x         = (const float*)d_in[0];
    const int*   ei        = (const int*)d_in[1];
    const float* W_l       = (const float*)d_in[2];
    const float* W_r       = (const float*)d_in[3];
    const float* att       = (const float*)d_in[4];
    const float* gat_bias  = (const float*)d_in[5];
    const float* gat_gamma = (const float*)d_in[6];
    const float* gat_beta  = (const float*)d_in[7];
    const float* cnn_W     = (const float*)d_in[8];
    const float* cnn_b     = (const float*)d_in[9];
    const float* conv_W    = (const float*)d_in[10];
    const float* conv_b    = (const float*)d_in[11];
    const float* cnn_gamma = (const float*)d_in[12];
    const float* cnn_beta  = (const float*)d_in[13];
    const float* res_W     = (const float*)d_in[14];
    const float* res_b     = (const float*)d_in[15];
    const float* fuse_gamma= (const float*)d_in[16];
    const float* fuse_beta = (const float*)d_in[17];

    int N = in_sizes[0] / IN_F;   // 16384
    int E = in_sizes[1] / 2;      // 262144

    char* ws = (char*)d_ws;
    size_t off = 0;
    ushort_t* xb     = (ushort_t*)(ws + off); off += (size_t)N * IN_F * 2;
    ushort_t* Wt     = (ushort_t*)(ws + off); off += (size_t)NCAT * IN_F * 2;
    ushort_t* Wt2    = (ushort_t*)(ws + off); off += (size_t)7 * 128 * 128 * 2;
    ushort_t* xlb    = (ushort_t*)(ws + off); off += (size_t)N * HF * 2;
    ushort_t* xrb    = (ushort_t*)(ws + off); off += (size_t)N * HF * 2;
    ushort_t* xcb    = (ushort_t*)(ws + off); off += (size_t)N * 128 * 2;
    ushort_t* resb   = (ushort_t*)(ws + off); off += (size_t)N * 128 * 2;
    int*  counts     = (int*)(ws + off);  off += (size_t)N * 4;
    int*  offs       = (int*)(ws + off);  off += (size_t)N * 4;
    int*  cursor     = (int*)(ws + off);  off += (size_t)N * 4;
    int*  srcs       = (int*)(ws + off);  off += (size_t)E * 4;
    float* hgat_ln   = (float*)(ws + off); off += (size_t)N * 128 * 4;

    hipMemsetAsync(counts, 0, (size_t)N * 4, stream);

    dim3 blk(256);
    int n_cvt = N * IN_F;
    int g1 = (n_cvt / 8 + 255) / 256;                       // cvt_x blocks
    int g2 = g1 + (NCAT * 256 + 7 * 128 * 128 + 255) / 256; // + weights blocks
    int g3 = g2 + (E + 255) / 256;                          // + hist blocks
    prep_kernel<<<g3, blk, 0, stream>>>(x, xb, n_cvt,
        W_l, W_r, cnn_W, res_W, conv_W, Wt, Wt2, ei, counts, E, g1, g2);

    scan_kernel<<<1, 1024, 0, stream>>>(counts, offs, cursor, N);
    scatter_kernel<<<(E + 255) / 256, blk, 0, stream>>>(ei, cursor, srcs, E);

    mfma_gemm<<<dim3(NCAT / 128, N / 128), blk, 0, stream>>>(
        xb, Wt, xlb, xrb, xcb, resb, N);

    gat_fused_kernel<<<(N + 3) / 4, blk, 0, stream>>>(
        xlb, xrb, srcs, offs, att, gat_bias, gat_gamma, gat_beta, hgat_ln, E, N);

    conv_fuse_kernel<<<dim3(16, 32), blk, 0, stream>>>(
        xcb, cnn_b, Wt2, hgat_ln, resb, conv_b, cnn_gamma, cnn_beta,
        res_b, fuse_gamma, fuse_beta, (float*)d_out);
}

// Round 8
// 144.114 us; speedup vs baseline: 4.8963x; 1.0465x over previous
//
#include <hip/hip_runtime.h>
#include <hip/hip_bf16.h>
#include <math.h>

#define IN_F 256
#define OUT_F 128
#define HEADS 4
#define HF 512    // HEADS*OUT_F
#define NCAT 1280 // 512 + 512 + 128 + 128

typedef __hip_bfloat16 bf16;
typedef unsigned short ushort_t;

using bf16x8 = __attribute__((ext_vector_type(8))) short;
using f32x4  = __attribute__((ext_vector_type(4))) float;

__device__ __forceinline__ float bflo(unsigned u) { return __uint_as_float(u << 16); }
__device__ __forceinline__ float bfhi(unsigned u) { return __uint_as_float(u & 0xffff0000u); }
__device__ __forceinline__ float bf2f(ushort_t u) { return __uint_as_float((unsigned)u << 16); }
__device__ __forceinline__ ushort_t f2bf(float f) {
    __hip_bfloat16 h = __float2bfloat16(f);
    return *reinterpret_cast<ushort_t*>(&h);
}

// async global->LDS, 16B per lane; dest = wave-uniform base + lane*16
__device__ __forceinline__ void gload16(const void* g, void* l) {
    __builtin_amdgcn_global_load_lds(
        (const __attribute__((address_space(1))) unsigned int*)g,
        (__attribute__((address_space(3))) unsigned int*)l, 16, 0, 0);
}

// sum over 16-lane row via DPP row_ror (all lanes end with full sum)
template <int CTRL>
__device__ __forceinline__ float dpp_add(float s) {
    int t = __builtin_amdgcn_update_dpp(0, __float_as_int(s), CTRL, 0xf, 0xf, true);
    return s + __int_as_float(t);
}
__device__ __forceinline__ float rowsum16(float s) {
    s = dpp_add<0x121>(s);
    s = dpp_add<0x122>(s);
    s = dpp_add<0x124>(s);
    s = dpp_add<0x128>(s);
    return s;
}

// ---------------- fused prep: cvt_x | build weights | hist ----------------
__global__ __launch_bounds__(256) void prep_kernel(
    const float* __restrict__ x, ushort_t* __restrict__ xb, int n_cvt,
    const float* __restrict__ Wl, const float* __restrict__ Wr,
    const float* __restrict__ Wc, const float* __restrict__ Wres,
    const float* __restrict__ Wconv,
    ushort_t* __restrict__ Wt, ushort_t* __restrict__ Wt2,
    const int* __restrict__ ei, int* __restrict__ counts, int E,
    int g1, int g2) {
    int b = blockIdx.x;
    if (b < g1) {
        int i = (b * 256 + threadIdx.x) * 8;
        if (i >= n_cvt) return;
        float4 a = *(const float4*)(x + i);
        float4 c = *(const float4*)(x + i + 4);
        uint4 o;
        o.x = f2bf(a.x) | ((unsigned)f2bf(a.y) << 16);
        o.y = f2bf(a.z) | ((unsigned)f2bf(a.w) << 16);
        o.z = f2bf(c.x) | ((unsigned)f2bf(c.y) << 16);
        o.w = f2bf(c.z) | ((unsigned)f2bf(c.w) << 16);
        *(uint4*)(xb + i) = o;
    } else if (b < g2) {
        int idx = (b - g1) * 256 + threadIdx.x;
        if (idx < NCAT * 256) {
            int n = idx >> 8, k = idx & 255;
            float v;
            if (n < 512)       v = Wl[(size_t)k * 512 + n];
            else if (n < 1024) v = Wr[(size_t)k * 512 + (n - 512)];
            else if (n < 1152) v = Wc[(size_t)k * 128 + (n - 1024)];
            else               v = Wres[(size_t)k * 128 + (n - 1152)];
            Wt[idx] = f2bf(v);
        } else {
            int j = idx - NCAT * 256;
            if (j < 7 * 128 * 128) {
                int k = j >> 14, o = (j >> 7) & 127, i = j & 127;
                Wt2[j] = f2bf(Wconv[((size_t)o * 128 + i) * 7 + k]);
            }
        }
    } else {
        int e = (b - g2) * 256 + threadIdx.x;
        if (e < E) atomicAdd(&counts[ei[E + e]], 1);
    }
}

// ---------------- MFMA GEMM, BK=64, global_load_lds + XOR swizzle ----------------
// LDS linear [128 rows][64 bf16 = 128B]; LDS[r][slot s] = global[r][s ^ (r&7)]
__global__ __launch_bounds__(256) void mfma_gemm(
    const ushort_t* __restrict__ A,   // [M][256] bf16
    const ushort_t* __restrict__ Wt,  // [1280][256] bf16
    ushort_t* __restrict__ xlb, ushort_t* __restrict__ xrb,
    ushort_t* __restrict__ xcb, ushort_t* __restrict__ resb,
    int M) {
    __shared__ __align__(1024) ushort_t As[128 * 64];
    __shared__ __align__(1024) ushort_t Bs[128 * 64];
    int tid = threadIdx.x;
    int lane = tid & 63, wid = tid >> 6;
    int wr = (wid >> 1) * 64, wc = (wid & 1) * 64;
    int brow = blockIdx.y * 128, bcol = blockIdx.x * 128;
    int srow = lane >> 3;      // staging: 8-row group row
    int sslot = lane & 7;      // staging: linear 16B slot
    int rl = lane & 15, kq = lane >> 4;
    f32x4 acc[4][4] = {};
    for (int k0 = 0; k0 < 256; k0 += 64) {
        #pragma unroll
        for (int j = 0; j < 4; ++j) {
            int r = (wid * 4 + j) * 8 + srow;
            int sl = sslot ^ (r & 7);
            gload16(A  + (size_t)(brow + r) * 256 + k0 + sl * 8,
                    (char*)As + (wid * 4 + j) * 1024);
            gload16(Wt + (size_t)(bcol + r) * 256 + k0 + sl * 8,
                    (char*)Bs + (wid * 4 + j) * 1024);
        }
        __syncthreads();   // drains vmcnt before barrier
        #pragma unroll
        for (int ks = 0; ks < 2; ++ks) {
            int cb = ks * 64 + kq * 16;   // byte col of this lane's k-fragment
            bf16x8 af[4], bfv[4];
            #pragma unroll
            for (int m = 0; m < 4; ++m) {
                int r = wr + m * 16 + rl;
                af[m] = *(const bf16x8*)((const char*)As + r * 128 + (cb ^ ((r & 7) << 4)));
            }
            #pragma unroll
            for (int n = 0; n < 4; ++n) {
                int r = wc + n * 16 + rl;
                bfv[n] = *(const bf16x8*)((const char*)Bs + r * 128 + (cb ^ ((r & 7) << 4)));
            }
            #pragma unroll
            for (int m = 0; m < 4; ++m)
                #pragma unroll
                for (int n = 0; n < 4; ++n)
                    acc[m][n] = __builtin_amdgcn_mfma_f32_16x16x32_bf16(
                        af[m], bfv[n], acc[m][n], 0, 0, 0);
        }
        __syncthreads();
    }
    ushort_t* dstp; int cstride, cb2;
    if (bcol < 512)       { dstp = xlb;  cstride = 512; cb2 = bcol; }
    else if (bcol < 1024) { dstp = xrb;  cstride = 512; cb2 = bcol - 512; }
    else if (bcol < 1152) { dstp = xcb;  cstride = 128; cb2 = bcol - 1024; }
    else                  { dstp = resb; cstride = 128; cb2 = bcol - 1152; }
    int rowb = (lane >> 4) * 4;
    #pragma unroll
    for (int m = 0; m < 4; ++m)
        #pragma unroll
        for (int n = 0; n < 4; ++n) {
            int col = cb2 + wc + n * 16 + rl;
            #pragma unroll
            for (int q = 0; q < 4; ++q) {
                int row = brow + wr + m * 16 + rowb + q;
                dstp[(size_t)row * cstride + col] = f2bf(acc[m][n][q]);
            }
        }
}

// ---------------- CSR build ----------------
__global__ __launch_bounds__(1024) void scan_kernel(
    const int* __restrict__ counts, int* __restrict__ offs,
    int* __restrict__ cursor, int N) {
    __shared__ int wsum[16];
    int t = threadIdx.x;
    int lane = t & 63, w = t >> 6;
    int base = t * 16;
    int local[16], s = 0;
    #pragma unroll
    for (int i = 0; i < 16; ++i) {
        int v = (base + i < N) ? counts[base + i] : 0;
        local[i] = v; s += v;
    }
    int sc = s;
    #pragma unroll
    for (int off = 1; off < 64; off <<= 1) {
        int v = __shfl_up(sc, off);
        if (lane >= off) sc += v;
    }
    if (lane == 63) wsum[w] = sc;
    __syncthreads();
    if (w == 0 && lane < 16) {
        int v = wsum[lane];
        int scv = v;
        #pragma unroll
        for (int off = 1; off < 16; off <<= 1) {
            int u = __shfl_up(scv, off);
            if (lane >= off) scv += u;
        }
        wsum[lane] = scv - v;
    }
    __syncthreads();
    int run = wsum[w] + sc - s;
    #pragma unroll
    for (int i = 0; i < 16; ++i) {
        if (base + i < N) { offs[base + i] = run; cursor[base + i] = run; }
        run += local[i];
    }
}

__global__ __launch_bounds__(256) void scatter_kernel(
    const int* __restrict__ ei, int* __restrict__ cursor,
    int* __restrict__ srcs, int E) {
    int e = blockIdx.x * 256 + threadIdx.x;
    if (e < E) {
        int d = ei[E + e];
        int p = atomicAdd(&cursor[d], 1);
        srcs[p] = ei[e];
    }
}

// ---------------- fused GAT: score + softmax + aggregate + bias/leaky/LN ----------------
__global__ __launch_bounds__(256) void gat_fused_kernel(
    const ushort_t* __restrict__ xlb, const ushort_t* __restrict__ xrb,
    const int* __restrict__ srcs, const int* __restrict__ offs,
    const float* __restrict__ att, const float* __restrict__ gat_bias,
    const float* __restrict__ gat_gamma, const float* __restrict__ gat_beta,
    float* __restrict__ hgat_ln, int E, int N) {
    int wid = (blockIdx.x * 256 + threadIdx.x) >> 6;
    int lane = threadIdx.x & 63;
    if (wid >= N) return;
    int d = wid;
    const uint4 rv = ((const uint4*)(xrb + (size_t)d * HF))[lane];
    float xr8[8];
    xr8[0] = bflo(rv.x); xr8[1] = bfhi(rv.x);
    xr8[2] = bflo(rv.y); xr8[3] = bfhi(rv.y);
    xr8[4] = bflo(rv.z); xr8[5] = bfhi(rv.z);
    xr8[6] = bflo(rv.w); xr8[7] = bfhi(rv.w);
    const float LOG2E = 1.44269504f;
    const float4 a0 = ((const float4*)att)[lane * 2];
    const float4 a1 = ((const float4*)att)[lane * 2 + 1];
    // pre-scale by log2(e): score lands in log2 domain -> bare v_exp_f32
    const float aw[8] = {a0.x * LOG2E, a0.y * LOG2E, a0.z * LOG2E, a0.w * LOG2E,
                         a1.x * LOG2E, a1.y * LOG2E, a1.z * LOG2E, a1.w * LOG2E};
    float acc[8] = {};
    float dn = 0.f;

    // leaky0.2(v) = 0.6v + 0.4|v|  (abs is a free src modifier)
    auto process = [&](uint4 lv) {
        float xl8[8];
        xl8[0] = bflo(lv.x); xl8[1] = bfhi(lv.x);
        xl8[2] = bflo(lv.y); xl8[3] = bfhi(lv.y);
        xl8[4] = bflo(lv.z); xl8[5] = bfhi(lv.z);
        xl8[6] = bflo(lv.w); xl8[7] = bfhi(lv.w);
        float s1 = 0.f, s2 = 0.f;
        #pragma unroll
        for (int j = 0; j < 8; ++j) {
            float v = xl8[j] + xr8[j];
            s1 = fmaf(v, aw[j], s1);
            s2 = fmaf(fabsf(v), aw[j], s2);
        }
        float s = fmaf(0.6f, s1, 0.4f * s2);
        s = rowsum16(s);
        float ex = exp2f(s);
        dn += ex;
        #pragma unroll
        for (int j = 0; j < 8; ++j) acc[j] = fmaf(ex, xl8[j], acc[j]);
    };

    process(((const uint4*)(xlb + (size_t)d * HF))[lane]);   // self-loop

    int start = offs[d];
    int end = (d == N - 1) ? E : offs[d + 1];
    int p = start;
    for (; p + 3 < end; p += 4) {
        int s0 = srcs[p], s1 = srcs[p + 1], s2 = srcs[p + 2], s3 = srcs[p + 3];
        uint4 l0 = ((const uint4*)(xlb + (size_t)s0 * HF))[lane];
        uint4 l1 = ((const uint4*)(xlb + (size_t)s1 * HF))[lane];
        uint4 l2 = ((const uint4*)(xlb + (size_t)s2 * HF))[lane];
        uint4 l3 = ((const uint4*)(xlb + (size_t)s3 * HF))[lane];
        process(l0); process(l1); process(l2); process(l3);
    }
    for (; p < end; ++p)
        process(((const uint4*)(xlb + (size_t)srcs[p] * HF))[lane]);

    float inv = 1.f / dn;
    float v[8];
    #pragma unroll
    for (int j = 0; j < 8; ++j) {
        float t2 = acc[j] * inv;
        t2 += __shfl_xor(t2, 16);
        t2 += __shfl_xor(t2, 32);
        v[j] = t2;
    }
    int h = lane >> 4;
    int col = (lane & 15) * 8 + 2 * h;
    float g0 = 0.25f * v[2 * h]     + gat_bias[col];
    float g1 = 0.25f * v[2 * h + 1] + gat_bias[col + 1];
    g0 = g0 > 0.f ? g0 : 0.01f * g0;
    g1 = g1 > 0.f ? g1 : 0.01f * g1;
    float s = g0 + g1;
    #pragma unroll
    for (int off = 32; off; off >>= 1) s += __shfl_xor(s, off);
    float mu = s * (1.f / 128.f);
    float d0 = g0 - mu, d1 = g1 - mu;
    float vs = d0 * d0 + d1 * d1;
    #pragma unroll
    for (int off = 32; off; off >>= 1) vs += __shfl_xor(vs, off);
    float rinv = rsqrtf(vs * (1.f / 128.f) + 1e-5f);
    hgat_ln[(size_t)d * 128 + col]     = d0 * rinv * gat_gamma[col]     + gat_beta[col];
    hgat_ln[(size_t)d * 128 + col + 1] = d1 * rinv * gat_gamma[col + 1] + gat_beta[col + 1];
}

// ---------------- MFMA conv1d + relu + LN(cnn) + fuse + LN -> out ----------------
// Bs linear [128 rows][128 bf16 = 256B], gload_lds; LDS[r][s] = global[r][s^(r&15)]
__global__ __launch_bounds__(256) void conv_fuse_kernel(
    const ushort_t* __restrict__ xcb, const float* __restrict__ cnn_b,
    const ushort_t* __restrict__ Wt2,
    const float* __restrict__ hgat_ln, const ushort_t* __restrict__ resb,
    const float* __restrict__ conv_b,
    const float* __restrict__ cnn_gamma, const float* __restrict__ cnn_beta,
    const float* __restrict__ res_b,
    const float* __restrict__ fuse_gamma, const float* __restrict__ fuse_beta,
    float* __restrict__ out) {
    __shared__ ushort_t As[38][136];   // rows l0-3 .. l0+34 (padded, VALU-staged)
    __shared__ __align__(1024) ushort_t Bs[128 * 128];
    __shared__ float hbuf[32][129];
    int tid = threadIdx.x;
    int lane = tid & 63, wid = tid >> 6;
    int wr = (wid >> 1) * 16, wc = (wid & 1) * 64;
    int b = blockIdx.y, l0 = blockIdx.x * 32;
    for (int u = tid; u < 38 * 16; u += 256) {
        int r = u >> 4, seg = u & 15;
        int l = l0 - 3 + r;
        uint4 o4 = make_uint4(0, 0, 0, 0);
        if (l >= 0 && l < 512) {
            uint4 v = *(const uint4*)(xcb + (size_t)(b * 512 + l) * 128 + seg * 8);
            float4 b0 = *(const float4*)(cnn_b + seg * 8);
            float4 b1 = *(const float4*)(cnn_b + seg * 8 + 4);
            o4.x = f2bf(bflo(v.x) + b0.x) | ((unsigned)f2bf(bfhi(v.x) + b0.y) << 16);
            o4.y = f2bf(bflo(v.y) + b0.z) | ((unsigned)f2bf(bfhi(v.y) + b0.w) << 16);
            o4.z = f2bf(bflo(v.z) + b1.x) | ((unsigned)f2bf(bfhi(v.z) + b1.y) << 16);
            o4.w = f2bf(bflo(v.w) + b1.z) | ((unsigned)f2bf(bfhi(v.w) + b1.w) << 16);
        }
        *(uint4*)&As[r][seg * 8] = o4;
    }
    f32x4 acc[4] = {};
    int rl = lane & 15, kb = (lane >> 4) * 8;
    int sr4 = lane >> 4, ss = lane & 15;
    for (int k = 0; k < 7; ++k) {
        __syncthreads();
        #pragma unroll
        for (int j = 0; j < 8; ++j) {
            int r = (wid * 8 + j) * 4 + sr4;
            int sl = ss ^ (r & 15);
            gload16(Wt2 + ((size_t)(k * 128 + r)) * 128 + sl * 8,
                    (char*)Bs + (wid * 8 + j) * 1024);
        }
        __syncthreads();
        #pragma unroll
        for (int kk = 0; kk < 4; ++kk) {
            bf16x8 af = *(const bf16x8*)&As[wr + rl + k][kk * 32 + kb];
            int cbyte = kk * 64 + (lane >> 4) * 16;
            #pragma unroll
            for (int n = 0; n < 4; ++n) {
                int r = wc + n * 16 + rl;
                bf16x8 bfr = *(const bf16x8*)((const char*)Bs + r * 256
                                              + (cbyte ^ ((r & 15) << 4)));
                acc[n] = __builtin_amdgcn_mfma_f32_16x16x32_bf16(af, bfr, acc[n], 0, 0, 0);
            }
        }
    }
    __syncthreads();
    int rowb = (lane >> 4) * 4;
    #pragma unroll
    for (int n = 0; n < 4; ++n) {
        int col = wc + n * 16 + rl;
        float cb = conv_b[col];
        #pragma unroll
        for (int q = 0; q < 4; ++q) {
            int r = wr + rowb + q;
            hbuf[r][col] = fmaxf(acc[n][q] + cb, 0.f);
        }
    }
    __syncthreads();
    for (int r = wid * 8; r < wid * 8 + 8; ++r) {
        int grow = b * 512 + l0 + r;
        float h0 = hbuf[r][lane], h1 = hbuf[r][lane + 64];
        float s = h0 + h1;
        #pragma unroll
        for (int off = 32; off; off >>= 1) s += __shfl_xor(s, off);
        float mu = s * (1.f / 128.f);
        float d0 = h0 - mu, d1 = h1 - mu;
        float vs = d0 * d0 + d1 * d1;
        #pragma unroll
        for (int off = 32; off; off >>= 1) vs += __shfl_xor(vs, off);
        float inv = rsqrtf(vs * (1.f / 128.f) + 1e-5f);
        float hcn0 = d0 * inv * cnn_gamma[lane]      + cnn_beta[lane];
        float hcn1 = d1 * inv * cnn_gamma[lane + 64] + cnn_beta[lane + 64];
        size_t base = (size_t)grow * 128;
        float v0 = hgat_ln[base + lane]      + hcn0
                 + bf2f(resb[base + lane])      + res_b[lane];
        float v1 = hgat_ln[base + lane + 64] + hcn1
                 + bf2f(resb[base + lane + 64]) + res_b[lane + 64];
        s = v0 + v1;
        #pragma unroll
        for (int off = 32; off; off >>= 1) s += __shfl_xor(s, off);
        mu = s * (1.f / 128.f);
        d0 = v0 - mu; d1 = v1 - mu;
        vs = d0 * d0 + d1 * d1;
        #pragma unroll
        for (int off = 32; off; off >>= 1) vs += __shfl_xor(vs, off);
        inv = rsqrtf(vs * (1.f / 128.f) + 1e-5f);
        out[base + lane]      = d0 * inv * fuse_gamma[lane]      + fuse_beta[lane];
        out[base + lane + 64] = d1 * inv * fuse_gamma[lane + 64] + fuse_beta[lane + 64];
    }
}

extern "C" void kernel_launch(void* const* d_in, const int* in_sizes, int n_in,
                              void* d_out, int out_size, void* d_ws, size_t ws_size,
                              hipStream_t stream) {
    const float* x         = (const float*)d_in[0];
    const int*   ei        = (const int*)d_in[1];
    const float* W_l       = (const float*)d_in[2];
    const float* W_r       = (const float*)d_in[3];
    const float* att       = (const float*)d_in[4];
    const float* gat_bias  = (const float*)d_in[5];
    const float* gat_gamma = (const float*)d_in[6];
    const float* gat_beta  = (const float*)d_in[7];
    const float* cnn_W     = (const float*)d_in[8];
    const float* cnn_b     = (const float*)d_in[9];
    const float* conv_W    = (const float*)d_in[10];
    const float* conv_b    = (const float*)d_in[11];
    const float* cnn_gamma = (const float*)d_in[12];
    const float* cnn_beta  = (const float*)d_in[13];
    const float* res_W     = (const float*)d_in[14];
    const float* res_b     = (const float*)d_in[15];
    const float* fuse_gamma= (const float*)d_in[16];
    const float* fuse_beta = (const float*)d_in[17];

    int N = in_sizes[0] / IN_F;   // 16384
    int E = in_sizes[1] / 2;      // 262144

    char* ws = (char*)d_ws;
    size_t off = 0;
    ushort_t* xb     = (ushort_t*)(ws + off); off += (size_t)N * IN_F * 2;
    ushort_t* Wt     = (ushort_t*)(ws + off); off += (size_t)NCAT * IN_F * 2;
    ushort_t* Wt2    = (ushort_t*)(ws + off); off += (size_t)7 * 128 * 128 * 2;
    ushort_t* xlb    = (ushort_t*)(ws + off); off += (size_t)N * HF * 2;
    ushort_t* xrb    = (ushort_t*)(ws + off); off += (size_t)N * HF * 2;
    ushort_t* xcb    = (ushort_t*)(ws + off); off += (size_t)N * 128 * 2;
    ushort_t* resb   = (ushort_t*)(ws + off); off += (size_t)N * 128 * 2;
    int*  counts     = (int*)(ws + off);  off += (size_t)N * 4;
    int*  offs       = (int*)(ws + off);  off += (size_t)N * 4;
    int*  cursor     = (int*)(ws + off);  off += (size_t)N * 4;
    int*  srcs       = (int*)(ws + off);  off += (size_t)E * 4;
    float* hgat_ln   = (float*)(ws + off); off += (size_t)N * 128 * 4;

    hipMemsetAsync(counts, 0, (size_t)N * 4, stream);

    dim3 blk(256);
    int n_cvt = N * IN_F;
    int g1 = (n_cvt / 8 + 255) / 256;
    int g2 = g1 + (NCAT * 256 + 7 * 128 * 128 + 255) / 256;
    int g3 = g2 + (E + 255) / 256;
    prep_kernel<<<g3, blk, 0, stream>>>(x, xb, n_cvt,
        W_l, W_r, cnn_W, res_W, conv_W, Wt, Wt2, ei, counts, E, g1, g2);

    scan_kernel<<<1, 1024, 0, stream>>>(counts, offs, cursor, N);
    scatter_kernel<<<(E + 255) / 256, blk, 0, stream>>>(ei, cursor, srcs, E);

    mfma_gemm<<<dim3(NCAT / 128, N / 128), blk, 0, stream>>>(
        xb, Wt, xlb, xrb, xcb, resb, N);

    gat_fused_kernel<<<(N + 3) / 4, blk, 0, stream>>>(
        xlb, xrb, srcs, offs, att, gat_bias, gat_gamma, gat_beta, hgat_ln, E, N);

    conv_fuse_kernel<<<dim3(16, 32), blk, 0, stream>>>(
        xcb, cnn_b, Wt2, hgat_ln, resb, conv_b, cnn_gamma, cnn_beta,
        res_b, fuse_gamma, fuse_beta, (float*)d_out);
}

// Round 10
// 142.945 us; speedup vs baseline: 4.9363x; 1.0082x over previous
//
#include <hip/hip_runtime.h>
#include <hip/hip_bf16.h>
#include <math.h>

#define IN_F 256
#define OUT_F 128
#define HEADS 4
#define HF 512    // HEADS*OUT_F
#define NCAT 1280 // 512 + 512 + 128 + 128

typedef __hip_bfloat16 bf16;
typedef unsigned short ushort_t;

using bf16x8 = __attribute__((ext_vector_type(8))) short;
using f32x4  = __attribute__((ext_vector_type(4))) float;
using f32v2  = __attribute__((ext_vector_type(2))) float;

__device__ __forceinline__ float bflo(unsigned u) { return __uint_as_float(u << 16); }
__device__ __forceinline__ float bfhi(unsigned u) { return __uint_as_float(u & 0xffff0000u); }
__device__ __forceinline__ float bf2f(ushort_t u) { return __uint_as_float((unsigned)u << 16); }
__device__ __forceinline__ ushort_t f2bf(float f) {
    __hip_bfloat16 h = __float2bfloat16(f);
    return *reinterpret_cast<ushort_t*>(&h);
}

// async global->LDS, 16B per lane; dest = wave-uniform base + lane*16
__device__ __forceinline__ void gload16(const void* g, void* l) {
    __builtin_amdgcn_global_load_lds(
        (const __attribute__((address_space(1))) unsigned int*)g,
        (__attribute__((address_space(3))) unsigned int*)l, 16, 0, 0);
}

// sum over 16-lane row via DPP row_ror (all lanes end with full sum)
template <int CTRL>
__device__ __forceinline__ float dpp_add(float s) {
    int t = __builtin_amdgcn_update_dpp(0, __float_as_int(s), CTRL, 0xf, 0xf, true);
    return s + __int_as_float(t);
}
__device__ __forceinline__ float rowsum16(float s) {
    s = dpp_add<0x121>(s);
    s = dpp_add<0x122>(s);
    s = dpp_add<0x124>(s);
    s = dpp_add<0x128>(s);
    return s;
}

// ---------------- fused prep: cvt_x | build weights | hist ----------------
__global__ __launch_bounds__(256) void prep_kernel(
    const float* __restrict__ x, ushort_t* __restrict__ xb, int n_cvt,
    const float* __restrict__ Wl, const float* __restrict__ Wr,
    const float* __restrict__ Wc, const float* __restrict__ Wres,
    const float* __restrict__ Wconv,
    ushort_t* __restrict__ Wt, ushort_t* __restrict__ Wt2,
    const int* __restrict__ ei, int* __restrict__ counts, int E,
    int g1, int g2) {
    int b = blockIdx.x;
    if (b < g1) {
        int i = (b * 256 + threadIdx.x) * 8;
        if (i >= n_cvt) return;
        float4 a = *(const float4*)(x + i);
        float4 c = *(const float4*)(x + i + 4);
        uint4 o;
        o.x = f2bf(a.x) | ((unsigned)f2bf(a.y) << 16);
        o.y = f2bf(a.z) | ((unsigned)f2bf(a.w) << 16);
        o.z = f2bf(c.x) | ((unsigned)f2bf(c.y) << 16);
        o.w = f2bf(c.z) | ((unsigned)f2bf(c.w) << 16);
        *(uint4*)(xb + i) = o;
    } else if (b < g2) {
        int idx = (b - g1) * 256 + threadIdx.x;
        if (idx < NCAT * 256) {
            int n = idx >> 8, k = idx & 255;
            float v;
            if (n < 512)       v = Wl[(size_t)k * 512 + n];
            else if (n < 1024) v = Wr[(size_t)k * 512 + (n - 512)];
            else if (n < 1152) v = Wc[(size_t)k * 128 + (n - 1024)];
            else               v = Wres[(size_t)k * 128 + (n - 1152)];
            Wt[idx] = f2bf(v);
        } else {
            int j = idx - NCAT * 256;
            if (j < 7 * 128 * 128) {
                int k = j >> 14, o = (j >> 7) & 127, i = j & 127;
                Wt2[j] = f2bf(Wconv[((size_t)o * 128 + i) * 7 + k]);
            }
        }
    } else {
        int e = (b - g2) * 256 + threadIdx.x;
        if (e < E) atomicAdd(&counts[ei[E + e]], 1);
    }
}

// ---------------- MFMA GEMM, BK=64, global_load_lds + XOR swizzle ----------------
__global__ __launch_bounds__(256) void mfma_gemm(
    const ushort_t* __restrict__ A,   // [M][256] bf16
    const ushort_t* __restrict__ Wt,  // [1280][256] bf16
    ushort_t* __restrict__ xlb, ushort_t* __restrict__ xrb,
    ushort_t* __restrict__ xcb, ushort_t* __restrict__ resb,
    int M) {
    __shared__ __align__(1024) ushort_t As[128 * 64];
    __shared__ __align__(1024) ushort_t Bs[128 * 64];
    int tid = threadIdx.x;
    int lane = tid & 63, wid = tid >> 6;
    int wr = (wid >> 1) * 64, wc = (wid & 1) * 64;
    int brow = blockIdx.y * 128, bcol = blockIdx.x * 128;
    int srow = lane >> 3;
    int sslot = lane & 7;
    int rl = lane & 15, kq = lane >> 4;
    f32x4 acc[4][4] = {};
    for (int k0 = 0; k0 < 256; k0 += 64) {
        #pragma unroll
        for (int j = 0; j < 4; ++j) {
            int r = (wid * 4 + j) * 8 + srow;
            int sl = sslot ^ (r & 7);
            gload16(A  + (size_t)(brow + r) * 256 + k0 + sl * 8,
                    (char*)As + (wid * 4 + j) * 1024);
            gload16(Wt + (size_t)(bcol + r) * 256 + k0 + sl * 8,
                    (char*)Bs + (wid * 4 + j) * 1024);
        }
        __syncthreads();
        #pragma unroll
        for (int ks = 0; ks < 2; ++ks) {
            int cb = ks * 64 + kq * 16;
            bf16x8 af[4], bfv[4];
            #pragma unroll
            for (int m = 0; m < 4; ++m) {
                int r = wr + m * 16 + rl;
                af[m] = *(const bf16x8*)((const char*)As + r * 128 + (cb ^ ((r & 7) << 4)));
            }
            #pragma unroll
            for (int n = 0; n < 4; ++n) {
                int r = wc + n * 16 + rl;
                bfv[n] = *(const bf16x8*)((const char*)Bs + r * 128 + (cb ^ ((r & 7) << 4)));
            }
            #pragma unroll
            for (int m = 0; m < 4; ++m)
                #pragma unroll
                for (int n = 0; n < 4; ++n)
                    acc[m][n] = __builtin_amdgcn_mfma_f32_16x16x32_bf16(
                        af[m], bfv[n], acc[m][n], 0, 0, 0);
        }
        __syncthreads();
    }
    ushort_t* dstp; int cstride, cb2;
    if (bcol < 512)       { dstp = xlb;  cstride = 512; cb2 = bcol; }
    else if (bcol < 1024) { dstp = xrb;  cstride = 512; cb2 = bcol - 512; }
    else if (bcol < 1152) { dstp = xcb;  cstride = 128; cb2 = bcol - 1024; }
    else                  { dstp = resb; cstride = 128; cb2 = bcol - 1152; }
    int rowb = (lane >> 4) * 4;
    #pragma unroll
    for (int m = 0; m < 4; ++m)
        #pragma unroll
        for (int n = 0; n < 4; ++n) {
            int col = cb2 + wc + n * 16 + rl;
            #pragma unroll
            for (int q = 0; q < 4; ++q) {
                int row = brow + wr + m * 16 + rowb + q;
                dstp[(size_t)row * cstride + col] = f2bf(acc[m][n][q]);
            }
        }
}

// ---------------- CSR build ----------------
__global__ __launch_bounds__(1024) void scan_kernel(
    const int* __restrict__ counts, int* __restrict__ offs,
    int* __restrict__ cursor, int N) {
    __shared__ int wsum[16];
    int t = threadIdx.x;
    int lane = t & 63, w = t >> 6;
    int base = t * 16;
    int local[16], s = 0;
    #pragma unroll
    for (int i = 0; i < 16; ++i) {
        int v = (base + i < N) ? counts[base + i] : 0;
        local[i] = v; s += v;
    }
    int sc = s;
    #pragma unroll
    for (int off = 1; off < 64; off <<= 1) {
        int v = __shfl_up(sc, off);
        if (lane >= off) sc += v;
    }
    if (lane == 63) wsum[w] = sc;
    __syncthreads();
    if (w == 0 && lane < 16) {
        int v = wsum[lane];
        int scv = v;
        #pragma unroll
        for (int off = 1; off < 16; off <<= 1) {
            int u = __shfl_up(scv, off);
            if (lane >= off) scv += u;
        }
        wsum[lane] = scv - v;
    }
    __syncthreads();
    int run = wsum[w] + sc - s;
    #pragma unroll
    for (int i = 0; i < 16; ++i) {
        if (base + i < N) { offs[base + i] = run; cursor[base + i] = run; }
        run += local[i];
    }
}

__global__ __launch_bounds__(256) void scatter_kernel(
    const int* __restrict__ ei, int* __restrict__ cursor,
    int* __restrict__ srcs, int E) {
    int e = blockIdx.x * 256 + threadIdx.x;
    if (e < E) {
        int d = ei[E + e];
        int p = atomicAdd(&cursor[d], 1);
        srcs[p] = ei[e];
    }
}

// ---------------- MFMA conv1d + relu + LN(cnn) -> hcn_ln (bf16) ----------------
__global__ __launch_bounds__(256) void conv_ln_kernel(
    const ushort_t* __restrict__ xcb, const float* __restrict__ cnn_b,
    const ushort_t* __restrict__ Wt2, const float* __restrict__ conv_b,
    const float* __restrict__ cnn_gamma, const float* __restrict__ cnn_beta,
    ushort_t* __restrict__ hcn_ln) {
    __shared__ ushort_t As[38][136];
    __shared__ __align__(1024) ushort_t Bs[128 * 128];
    __shared__ float hbuf[32][129];
    int tid = threadIdx.x;
    int lane = tid & 63, wid = tid >> 6;
    int wr = (wid >> 1) * 16, wc = (wid & 1) * 64;
    int b = blockIdx.y, l0 = blockIdx.x * 32;
    for (int u = tid; u < 38 * 16; u += 256) {
        int r = u >> 4, seg = u & 15;
        int l = l0 - 3 + r;
        uint4 o4 = make_uint4(0, 0, 0, 0);
        if (l >= 0 && l < 512) {
            uint4 v = *(const uint4*)(xcb + (size_t)(b * 512 + l) * 128 + seg * 8);
            float4 b0 = *(const float4*)(cnn_b + seg * 8);
            float4 b1 = *(const float4*)(cnn_b + seg * 8 + 4);
            o4.x = f2bf(bflo(v.x) + b0.x) | ((unsigned)f2bf(bfhi(v.x) + b0.y) << 16);
            o4.y = f2bf(bflo(v.y) + b0.z) | ((unsigned)f2bf(bfhi(v.y) + b0.w) << 16);
            o4.z = f2bf(bflo(v.z) + b1.x) | ((unsigned)f2bf(bfhi(v.z) + b1.y) << 16);
            o4.w = f2bf(bflo(v.w) + b1.z) | ((unsigned)f2bf(bfhi(v.w) + b1.w) << 16);
        }
        *(uint4*)&As[r][seg * 8] = o4;
    }
    f32x4 acc[4] = {};
    int rl = lane & 15, kb = (lane >> 4) * 8;
    int sr4 = lane >> 4, ss = lane & 15;
    for (int k = 0; k < 7; ++k) {
        __syncthreads();
        #pragma unroll
        for (int j = 0; j < 8; ++j) {
            int r = (wid * 8 + j) * 4 + sr4;
            int sl = ss ^ (r & 15);
            gload16(Wt2 + ((size_t)(k * 128 + r)) * 128 + sl * 8,
                    (char*)Bs + (wid * 8 + j) * 1024);
        }
        __syncthreads();
        #pragma unroll
        for (int kk = 0; kk < 4; ++kk) {
            bf16x8 af = *(const bf16x8*)&As[wr + rl + k][kk * 32 + kb];
            int cbyte = kk * 64 + (lane >> 4) * 16;
            #pragma unroll
            for (int n = 0; n < 4; ++n) {
                int r = wc + n * 16 + rl;
                bf16x8 bfr = *(const bf16x8*)((const char*)Bs + r * 256
                                              + (cbyte ^ ((r & 15) << 4)));
                acc[n] = __builtin_amdgcn_mfma_f32_16x16x32_bf16(af, bfr, acc[n], 0, 0, 0);
            }
        }
    }
    __syncthreads();
    int rowb = (lane >> 4) * 4;
    #pragma unroll
    for (int n = 0; n < 4; ++n) {
        int col = wc + n * 16 + rl;
        float cb = conv_b[col];
        #pragma unroll
        for (int q = 0; q < 4; ++q) {
            int r = wr + rowb + q;
            hbuf[r][col] = fmaxf(acc[n][q] + cb, 0.f);
        }
    }
    __syncthreads();
    for (int r = wid * 8; r < wid * 8 + 8; ++r) {
        int grow = b * 512 + l0 + r;
        float h0 = hbuf[r][lane], h1 = hbuf[r][lane + 64];
        float s = h0 + h1;
        #pragma unroll
        for (int off = 32; off; off >>= 1) s += __shfl_xor(s, off);
        float mu = s * (1.f / 128.f);
        float d0 = h0 - mu, d1 = h1 - mu;
        float vs = d0 * d0 + d1 * d1;
        #pragma unroll
        for (int off = 32; off; off >>= 1) vs += __shfl_xor(vs, off);
        float inv = rsqrtf(vs * (1.f / 128.f) + 1e-5f);
        size_t base = (size_t)grow * 128;
        hcn_ln[base + lane]      = f2bf(d0 * inv * cnn_gamma[lane]      + cnn_beta[lane]);
        hcn_ln[base + lane + 64] = f2bf(d1 * inv * cnn_gamma[lane + 64] + cnn_beta[lane + 64]);
    }
}

// ---------------- fused GAT + final fuse/LN -> out ----------------
__global__ __launch_bounds__(256) void gat_final_kernel(
    const ushort_t* __restrict__ xlb, const ushort_t* __restrict__ xrb,
    const int* __restrict__ srcs, const int* __restrict__ offs,
    const float* __restrict__ att, const float* __restrict__ gat_bias,
    const float* __restrict__ gat_gamma, const float* __restrict__ gat_beta,
    const ushort_t* __restrict__ hcn_ln, const ushort_t* __restrict__ resb,
    const float* __restrict__ res_b,
    const float* __restrict__ fuse_gamma, const float* __restrict__ fuse_beta,
    float* __restrict__ out, int E, int N) {
    int wid = (blockIdx.x * 256 + threadIdx.x) >> 6;
    int lane = threadIdx.x & 63;
    if (wid >= N) return;
    int d = wid;
    const uint4 rv = ((const uint4*)(xrb + (size_t)d * HF))[lane];
    f32v2 xr2[4];
    xr2[0] = f32v2{bflo(rv.x), bfhi(rv.x)};
    xr2[1] = f32v2{bflo(rv.y), bfhi(rv.y)};
    xr2[2] = f32v2{bflo(rv.z), bfhi(rv.z)};
    xr2[3] = f32v2{bflo(rv.w), bfhi(rv.w)};
    const float LOG2E = 1.44269504f;
    const float4 a0 = ((const float4*)att)[lane * 2];
    const float4 a1 = ((const float4*)att)[lane * 2 + 1];
    f32v2 aw2[4] = {f32v2{a0.x, a0.y} * LOG2E, f32v2{a0.z, a0.w} * LOG2E,
                    f32v2{a1.x, a1.y} * LOG2E, f32v2{a1.z, a1.w} * LOG2E};
    f32v2 acc2[4] = {};
    float dn = 0.f;

    // leaky0.2(v)*a = a*(0.6v + 0.4|v|); packed f32 pairs -> v_pk_fma_f32
    auto process = [&](uint4 lv) {
        f32v2 xl2[4];
        xl2[0] = f32v2{bflo(lv.x), bfhi(lv.x)};
        xl2[1] = f32v2{bflo(lv.y), bfhi(lv.y)};
        xl2[2] = f32v2{bflo(lv.z), bfhi(lv.z)};
        xl2[3] = f32v2{bflo(lv.w), bfhi(lv.w)};
        f32v2 s1 = {0.f, 0.f}, s2 = {0.f, 0.f};
        #pragma unroll
        for (int j = 0; j < 4; ++j) {
            f32v2 v = xl2[j] + xr2[j];
            s1 = __builtin_elementwise_fma(v, aw2[j], s1);
            s2 = __builtin_elementwise_fma(__builtin_elementwise_abs(v), aw2[j], s2);
        }
        float s = fmaf(0.6f, s1.x + s1.y, 0.4f * (s2.x + s2.y));
        s = rowsum16(s);
        float ex = exp2f(s);
        dn += ex;
        f32v2 exv = {ex, ex};
        #pragma unroll
        for (int j = 0; j < 4; ++j)
            acc2[j] = __builtin_elementwise_fma(exv, xl2[j], acc2[j]);
    };

    process(((const uint4*)(xlb + (size_t)d * HF))[lane]);   // self-loop

    int start = offs[d];
    int end = (d == N - 1) ? E : offs[d + 1];
    int p = start;
    for (; p + 3 < end; p += 4) {
        int s0 = srcs[p], s1 = srcs[p + 1], s2 = srcs[p + 2], s3 = srcs[p + 3];
        uint4 l0 = ((const uint4*)(xlb + (size_t)s0 * HF))[lane];
        uint4 l1 = ((const uint4*)(xlb + (size_t)s1 * HF))[lane];
        uint4 l2 = ((const uint4*)(xlb + (size_t)s2 * HF))[lane];
        uint4 l3 = ((const uint4*)(xlb + (size_t)s3 * HF))[lane];
        process(l0); process(l1); process(l2); process(l3);
    }
    for (; p < end; ++p)
        process(((const uint4*)(xlb + (size_t)srcs[p] * HF))[lane]);

    float inv = 1.f / dn;
    float v[8];
    #pragma unroll
    for (int j = 0; j < 4; ++j) {
        float tx = acc2[j].x * inv, ty = acc2[j].y * inv;
        tx += __shfl_xor(tx, 16); tx += __shfl_xor(tx, 32);
        ty += __shfl_xor(ty, 16); ty += __shfl_xor(ty, 32);
        v[2 * j] = tx; v[2 * j + 1] = ty;
    }
    int h = lane >> 4;
    int col = (lane & 15) * 8 + 2 * h;
    float g0 = 0.25f * v[2 * h]     + gat_bias[col];
    float g1 = 0.25f * v[2 * h + 1] + gat_bias[col + 1];
    g0 = g0 > 0.f ? g0 : 0.01f * g0;
    g1 = g1 > 0.f ? g1 : 0.01f * g1;
    // LN(gat)
    float s = g0 + g1;
    #pragma unroll
    for (int off = 32; off; off >>= 1) s += __shfl_xor(s, off);
    float mu = s * (1.f / 128.f);
    float d0 = g0 - mu, d1 = g1 - mu;
    float vs = d0 * d0 + d1 * d1;
    #pragma unroll
    for (int off = 32; off; off >>= 1) vs += __shfl_xor(vs, off);
    float rinv = rsqrtf(vs * (1.f / 128.f) + 1e-5f);
    float hg0 = d0 * rinv * gat_gamma[col]     + gat_beta[col];
    float hg1 = d1 * rinv * gat_gamma[col + 1] + gat_beta[col + 1];
    // fuse: + hcn_ln + res + res_b, then LN(fuse)
    size_t base = (size_t)d * 128 + col;
    unsigned hcu = *(const unsigned*)(hcn_ln + base);
    unsigned rsu = *(const unsigned*)(resb + base);
    float v0 = hg0 + bflo(hcu) + bflo(rsu) + res_b[col];
    float v1 = hg1 + bfhi(hcu) + bfhi(rsu) + res_b[col + 1];
    s = v0 + v1;
    #pragma unroll
    for (int off = 32; off; off >>= 1) s += __shfl_xor(s, off);
    mu = s * (1.f / 128.f);
    d0 = v0 - mu; d1 = v1 - mu;
    vs = d0 * d0 + d1 * d1;
    #pragma unroll
    for (int off = 32; off; off >>= 1) vs += __shfl_xor(vs, off);
    rinv = rsqrtf(vs * (1.f / 128.f) + 1e-5f);
    float2 o2 = make_float2(d0 * rinv * fuse_gamma[col]     + fuse_beta[col],
                            d1 * rinv * fuse_gamma[col + 1] + fuse_beta[col + 1]);
    *(float2*)(out + base) = o2;
}

extern "C" void kernel_launch(void* const* d_in, const int* in_sizes, int n_in,
                              void* d_out, int out_size, void* d_ws, size_t ws_size,
                              hipStream_t stream) {
    const float* x         = (const float*)d_in[0];
    const int*   ei        = (const int*)d_in[1];
    const float* W_l       = (const float*)d_in[2];
    const float* W_r       = (const float*)d_in[3];
    const float* att       = (const float*)d_in[4];
    const float* gat_bias  = (const float*)d_in[5];
    const float* gat_gamma = (const float*)d_in[6];
    const float* gat_beta  = (const float*)d_in[7];
    const float* cnn_W     = (const float*)d_in[8];
    const float* cnn_b     = (const float*)d_in[9];
    const float* conv_W    = (const float*)d_in[10];
    const float* conv_b    = (const float*)d_in[11];
    const float* cnn_gamma = (const float*)d_in[12];
    const float* cnn_beta  = (const float*)d_in[13];
    const float* res_W     = (const float*)d_in[14];
    const float* res_b     = (const float*)d_in[15];
    const float* fuse_gamma= (const float*)d_in[16];
    const float* fuse_beta = (const float*)d_in[17];

    int N = in_sizes[0] / IN_F;   // 16384
    int E = in_sizes[1] / 2;      // 262144

    char* ws = (char*)d_ws;
    size_t off = 0;
    ushort_t* xb     = (ushort_t*)(ws + off); off += (size_t)N * IN_F * 2;
    ushort_t* Wt     = (ushort_t*)(ws + off); off += (size_t)NCAT * IN_F * 2;
    ushort_t* Wt2    = (ushort_t*)(ws + off); off += (size_t)7 * 128 * 128 * 2;
    ushort_t* xlb    = (ushort_t*)(ws + off); off += (size_t)N * HF * 2;
    ushort_t* xrb    = (ushort_t*)(ws + off); off += (size_t)N * HF * 2;
    ushort_t* xcb    = (ushort_t*)(ws + off); off += (size_t)N * 128 * 2;
    ushort_t* resb   = (ushort_t*)(ws + off); off += (size_t)N * 128 * 2;
    ushort_t* hcn_ln = (ushort_t*)(ws + off); off += (size_t)N * 128 * 2;
    int*  counts     = (int*)(ws + off);  off += (size_t)N * 4;
    int*  offs       = (int*)(ws + off);  off += (size_t)N * 4;
    int*  cursor     = (int*)(ws + off);  off += (size_t)N * 4;
    int*  srcs       = (int*)(ws + off);  off += (size_t)E * 4;

    hipMemsetAsync(counts, 0, (size_t)N * 4, stream);

    dim3 blk(256);
    int n_cvt = N * IN_F;
    int g1 = (n_cvt / 8 + 255) / 256;
    int g2 = g1 + (NCAT * 256 + 7 * 128 * 128 + 255) / 256;
    int g3 = g2 + (E + 255) / 256;
    prep_kernel<<<g3, blk, 0, stream>>>(x, xb, n_cvt,
        W_l, W_r, cnn_W, res_W, conv_W, Wt, Wt2, ei, counts, E, g1, g2);

    scan_kernel<<<1, 1024, 0, stream>>>(counts, offs, cursor, N);
    scatter_kernel<<<(E + 255) / 256, blk, 0, stream>>>(ei, cursor, srcs, E);

    mfma_gemm<<<dim3(NCAT / 128, N / 128), blk, 0, stream>>>(
        xb, Wt, xlb, xrb, xcb, resb, N);

    conv_ln_kernel<<<dim3(16, 32), blk, 0, stream>>>(
        xcb, cnn_b, Wt2, conv_b, cnn_gamma, cnn_beta, hcn_ln);

    gat_final_kernel<<<(N + 3) / 4, blk, 0, stream>>>(
        xlb, xrb, srcs, offs, att, gat_bias, gat_gamma, gat_beta,
        hcn_ln, resb, res_b, fuse_gamma, fuse_beta, (float*)d_out, E, N);
}

// Round 11
// 142.289 us; speedup vs baseline: 4.9591x; 1.0046x over previous
//
#include <hip/hip_runtime.h>
#include <hip/hip_bf16.h>
#include <math.h>

#define IN_F 256
#define OUT_F 128
#define HEADS 4
#define HF 512    // HEADS*OUT_F
#define NCAT 1280 // 512 + 512 + 128 + 128

typedef __hip_bfloat16 bf16;
typedef unsigned short ushort_t;
typedef unsigned char uchar_t;

using bf16x8 = __attribute__((ext_vector_type(8))) short;
using f32x4  = __attribute__((ext_vector_type(4))) float;

__device__ __forceinline__ float bflo(unsigned u) { return __uint_as_float(u << 16); }
__device__ __forceinline__ float bfhi(unsigned u) { return __uint_as_float(u & 0xffff0000u); }
__device__ __forceinline__ float bf2f(ushort_t u) { return __uint_as_float((unsigned)u << 16); }
__device__ __forceinline__ ushort_t f2bf(float f) {
    __hip_bfloat16 h = __float2bfloat16(f);
    return *reinterpret_cast<ushort_t*>(&h);
}

// async global->LDS, 16B per lane; dest = wave-uniform base + lane*16
__device__ __forceinline__ void gload16(const void* g, void* l) {
    __builtin_amdgcn_global_load_lds(
        (const __attribute__((address_space(1))) unsigned int*)g,
        (__attribute__((address_space(3))) unsigned int*)l, 16, 0, 0);
}

// sum over 16-lane row via DPP row_ror (all lanes end with full sum)
template <int CTRL>
__device__ __forceinline__ float dpp_add(float s) {
    int t = __builtin_amdgcn_update_dpp(0, __float_as_int(s), CTRL, 0xf, 0xf, true);
    return s + __int_as_float(t);
}
__device__ __forceinline__ float rowsum16(float s) {
    s = dpp_add<0x121>(s);
    s = dpp_add<0x122>(s);
    s = dpp_add<0x124>(s);
    s = dpp_add<0x128>(s);
    return s;
}

// ---------------- fused prep: cvt_x | build weights | hist ----------------
__global__ __launch_bounds__(256) void prep_kernel(
    const float* __restrict__ x, ushort_t* __restrict__ xb, int n_cvt,
    const float* __restrict__ Wl, const float* __restrict__ Wr,
    const float* __restrict__ Wc, const float* __restrict__ Wres,
    const float* __restrict__ Wconv,
    ushort_t* __restrict__ Wt, ushort_t* __restrict__ Wt2,
    const int* __restrict__ ei, int* __restrict__ counts, int E,
    int g1, int g2) {
    int b = blockIdx.x;
    if (b < g1) {
        int i = (b * 256 + threadIdx.x) * 8;
        if (i >= n_cvt) return;
        float4 a = *(const float4*)(x + i);
        float4 c = *(const float4*)(x + i + 4);
        uint4 o;
        o.x = f2bf(a.x) | ((unsigned)f2bf(a.y) << 16);
        o.y = f2bf(a.z) | ((unsigned)f2bf(a.w) << 16);
        o.z = f2bf(c.x) | ((unsigned)f2bf(c.y) << 16);
        o.w = f2bf(c.z) | ((unsigned)f2bf(c.w) << 16);
        *(uint4*)(xb + i) = o;
    } else if (b < g2) {
        int idx = (b - g1) * 256 + threadIdx.x;
        if (idx < NCAT * 256) {
            int n = idx >> 8, k = idx & 255;
            float v;
            if (n < 512)       v = Wl[(size_t)k * 512 + n];
            else if (n < 1024) v = Wr[(size_t)k * 512 + (n - 512)];
            else if (n < 1152) v = Wc[(size_t)k * 128 + (n - 1024)];
            else               v = Wres[(size_t)k * 128 + (n - 1152)];
            Wt[idx] = f2bf(v);
        } else {
            int j = idx - NCAT * 256;
            if (j < 7 * 128 * 128) {
                int k = j >> 14, o = (j >> 7) & 127, i = j & 127;
                Wt2[j] = f2bf(Wconv[((size_t)o * 128 + i) * 7 + k]);
            }
        }
    } else {
        int e = (b - g2) * 256 + threadIdx.x;
        if (e < E) atomicAdd(&counts[ei[E + e]], 1);
    }
}

// ---------------- MFMA GEMM, BK=64, global_load_lds + XOR swizzle ----------------
// xl block (bcol<512) quantized to uint8 with per-(row,head) scale; others bf16
__global__ __launch_bounds__(256) void mfma_gemm(
    const ushort_t* __restrict__ A,   // [M][256] bf16
    const ushort_t* __restrict__ Wt,  // [1280][256] bf16
    uchar_t* __restrict__ xl8t, float* __restrict__ scales,
    ushort_t* __restrict__ xrb, ushort_t* __restrict__ xcb,
    ushort_t* __restrict__ resb, int M) {
    __shared__ __align__(1024) ushort_t As[128 * 64];
    __shared__ __align__(1024) ushort_t Bs[128 * 64];
    __shared__ float smax[128][2];
    int tid = threadIdx.x;
    int lane = tid & 63, wid = tid >> 6;
    int wr = (wid >> 1) * 64, wc = (wid & 1) * 64;
    int brow = blockIdx.y * 128, bcol = blockIdx.x * 128;
    int srow = lane >> 3;
    int sslot = lane & 7;
    int rl = lane & 15, kq = lane >> 4;
    f32x4 acc[4][4] = {};
    for (int k0 = 0; k0 < 256; k0 += 64) {
        #pragma unroll
        for (int j = 0; j < 4; ++j) {
            int r = (wid * 4 + j) * 8 + srow;
            int sl = sslot ^ (r & 7);
            gload16(A  + (size_t)(brow + r) * 256 + k0 + sl * 8,
                    (char*)As + (wid * 4 + j) * 1024);
            gload16(Wt + (size_t)(bcol + r) * 256 + k0 + sl * 8,
                    (char*)Bs + (wid * 4 + j) * 1024);
        }
        __syncthreads();
        #pragma unroll
        for (int ks = 0; ks < 2; ++ks) {
            int cb = ks * 64 + kq * 16;
            bf16x8 af[4], bfv[4];
            #pragma unroll
            for (int m = 0; m < 4; ++m) {
                int r = wr + m * 16 + rl;
                af[m] = *(const bf16x8*)((const char*)As + r * 128 + (cb ^ ((r & 7) << 4)));
            }
            #pragma unroll
            for (int n = 0; n < 4; ++n) {
                int r = wc + n * 16 + rl;
                bfv[n] = *(const bf16x8*)((const char*)Bs + r * 128 + (cb ^ ((r & 7) << 4)));
            }
            #pragma unroll
            for (int m = 0; m < 4; ++m)
                #pragma unroll
                for (int n = 0; n < 4; ++n)
                    acc[m][n] = __builtin_amdgcn_mfma_f32_16x16x32_bf16(
                        af[m], bfv[n], acc[m][n], 0, 0, 0);
        }
        __syncthreads();
    }
    int rowb = kq * 4;
    if (bcol < 512) {
        // ---- int8 quantized xl output with per-(row,head) scale ----
        int head = bcol >> 7;
        // per-(m,q) row max |.| over this wave's 64 cols
        float rmax[4][4];
        #pragma unroll
        for (int m = 0; m < 4; ++m)
            #pragma unroll
            for (int q = 0; q < 4; ++q) {
                float t = fabsf(acc[m][0][q]);
                t = fmaxf(t, fabsf(acc[m][1][q]));
                t = fmaxf(t, fabsf(acc[m][2][q]));
                t = fmaxf(t, fabsf(acc[m][3][q]));
                #pragma unroll
                for (int o = 1; o < 16; o <<= 1) t = fmaxf(t, __shfl_xor(t, o));
                rmax[m][q] = t;
            }
        if (rl == 0) {
            #pragma unroll
            for (int m = 0; m < 4; ++m)
                #pragma unroll
                for (int q = 0; q < 4; ++q)
                    smax[wr + m * 16 + rowb + q][wid & 1] = rmax[m][q];
        }
        __syncthreads();
        #pragma unroll
        for (int m = 0; m < 4; ++m)
            #pragma unroll
            for (int q = 0; q < 4; ++q) {
                int row = wr + m * 16 + rowb + q;
                float sm = fmaxf(fmaxf(smax[row][0], smax[row][1]), 1e-8f);
                float s = sm * (1.f / 127.f);
                float rs = 127.f / sm;
                if ((wid & 1) == 0 && rl == 0)
                    scales[(size_t)(brow + row) * 4 + head] = s;
                #pragma unroll
                for (int n = 0; n < 4; ++n) {
                    int col = bcol + wc + n * 16 + rl;
                    int qv = (int)rintf(acc[m][n][q] * rs) + 128;
                    xl8t[(size_t)(brow + row) * 512 + col] = (uchar_t)qv;
                }
            }
        return;
    }
    ushort_t* dstp; int cstride, cb2;
    if (bcol < 1024)      { dstp = xrb;  cstride = 512; cb2 = bcol - 512; }
    else if (bcol < 1152) { dstp = xcb;  cstride = 128; cb2 = bcol - 1024; }
    else                  { dstp = resb; cstride = 128; cb2 = bcol - 1152; }
    #pragma unroll
    for (int m = 0; m < 4; ++m)
        #pragma unroll
        for (int n = 0; n < 4; ++n) {
            int col = cb2 + wc + n * 16 + rl;
            #pragma unroll
            for (int q = 0; q < 4; ++q) {
                int row = brow + wr + m * 16 + rowb + q;
                dstp[(size_t)row * cstride + col] = f2bf(acc[m][n][q]);
            }
        }
}

// ---------------- CSR build ----------------
__global__ __launch_bounds__(1024) void scan_kernel(
    const int* __restrict__ counts, int* __restrict__ offs,
    int* __restrict__ cursor, int N) {
    __shared__ int wsum[16];
    int t = threadIdx.x;
    int lane = t & 63, w = t >> 6;
    int base = t * 16;
    int local[16], s = 0;
    #pragma unroll
    for (int i = 0; i < 16; ++i) {
        int v = (base + i < N) ? counts[base + i] : 0;
        local[i] = v; s += v;
    }
    int sc = s;
    #pragma unroll
    for (int off = 1; off < 64; off <<= 1) {
        int v = __shfl_up(sc, off);
        if (lane >= off) sc += v;
    }
    if (lane == 63) wsum[w] = sc;
    __syncthreads();
    if (w == 0 && lane < 16) {
        int v = wsum[lane];
        int scv = v;
        #pragma unroll
        for (int off = 1; off < 16; off <<= 1) {
            int u = __shfl_up(scv, off);
            if (lane >= off) scv += u;
        }
        wsum[lane] = scv - v;
    }
    __syncthreads();
    int run = wsum[w] + sc - s;
    #pragma unroll
    for (int i = 0; i < 16; ++i) {
        if (base + i < N) { offs[base + i] = run; cursor[base + i] = run; }
        run += local[i];
    }
}

__global__ __launch_bounds__(256) void scatter_kernel(
    const int* __restrict__ ei, int* __restrict__ cursor,
    int* __restrict__ srcs, int E) {
    int e = blockIdx.x * 256 + threadIdx.x;
    if (e < E) {
        int d = ei[E + e];
        int p = atomicAdd(&cursor[d], 1);
        srcs[p] = ei[e];
    }
}

// ---------------- MFMA conv1d + relu + LN(cnn) -> hcn_ln (bf16) ----------------
__global__ __launch_bounds__(256) void conv_ln_kernel(
    const ushort_t* __restrict__ xcb, const float* __restrict__ cnn_b,
    const ushort_t* __restrict__ Wt2, const float* __restrict__ conv_b,
    const float* __restrict__ cnn_gamma, const float* __restrict__ cnn_beta,
    ushort_t* __restrict__ hcn_ln) {
    __shared__ ushort_t As[38][136];
    __shared__ __align__(1024) ushort_t Bs[128 * 128];
    __shared__ float hbuf[32][129];
    int tid = threadIdx.x;
    int lane = tid & 63, wid = tid >> 6;
    int wr = (wid >> 1) * 16, wc = (wid & 1) * 64;
    int b = blockIdx.y, l0 = blockIdx.x * 32;
    for (int u = tid; u < 38 * 16; u += 256) {
        int r = u >> 4, seg = u & 15;
        int l = l0 - 3 + r;
        uint4 o4 = make_uint4(0, 0, 0, 0);
        if (l >= 0 && l < 512) {
            uint4 v = *(const uint4*)(xcb + (size_t)(b * 512 + l) * 128 + seg * 8);
            float4 b0 = *(const float4*)(cnn_b + seg * 8);
            float4 b1 = *(const float4*)(cnn_b + seg * 8 + 4);
            o4.x = f2bf(bflo(v.x) + b0.x) | ((unsigned)f2bf(bfhi(v.x) + b0.y) << 16);
            o4.y = f2bf(bflo(v.y) + b0.z) | ((unsigned)f2bf(bfhi(v.y) + b0.w) << 16);
            o4.z = f2bf(bflo(v.z) + b1.x) | ((unsigned)f2bf(bfhi(v.z) + b1.y) << 16);
            o4.w = f2bf(bflo(v.w) + b1.z) | ((unsigned)f2bf(bfhi(v.w) + b1.w) << 16);
        }
        *(uint4*)&As[r][seg * 8] = o4;
    }
    f32x4 acc[4] = {};
    int rl = lane & 15, kb = (lane >> 4) * 8;
    int sr4 = lane >> 4, ss = lane & 15;
    for (int k = 0; k < 7; ++k) {
        __syncthreads();
        #pragma unroll
        for (int j = 0; j < 8; ++j) {
            int r = (wid * 8 + j) * 4 + sr4;
            int sl = ss ^ (r & 15);
            gload16(Wt2 + ((size_t)(k * 128 + r)) * 128 + sl * 8,
                    (char*)Bs + (wid * 8 + j) * 1024);
        }
        __syncthreads();
        #pragma unroll
        for (int kk = 0; kk < 4; ++kk) {
            bf16x8 af = *(const bf16x8*)&As[wr + rl + k][kk * 32 + kb];
            int cbyte = kk * 64 + (lane >> 4) * 16;
            #pragma unroll
            for (int n = 0; n < 4; ++n) {
                int r = wc + n * 16 + rl;
                bf16x8 bfr = *(const bf16x8*)((const char*)Bs + r * 256
                                              + (cbyte ^ ((r & 15) << 4)));
                acc[n] = __builtin_amdgcn_mfma_f32_16x16x32_bf16(af, bfr, acc[n], 0, 0, 0);
            }
        }
    }
    __syncthreads();
    int rowb = (lane >> 4) * 4;
    #pragma unroll
    for (int n = 0; n < 4; ++n) {
        int col = wc + n * 16 + rl;
        float cb = conv_b[col];
        #pragma unroll
        for (int q = 0; q < 4; ++q) {
            int r = wr + rowb + q;
            hbuf[r][col] = fmaxf(acc[n][q] + cb, 0.f);
        }
    }
    __syncthreads();
    for (int r = wid * 8; r < wid * 8 + 8; ++r) {
        int grow = b * 512 + l0 + r;
        float h0 = hbuf[r][lane], h1 = hbuf[r][lane + 64];
        float s = h0 + h1;
        #pragma unroll
        for (int off = 32; off; off >>= 1) s += __shfl_xor(s, off);
        float mu = s * (1.f / 128.f);
        float d0 = h0 - mu, d1 = h1 - mu;
        float vs = d0 * d0 + d1 * d1;
        #pragma unroll
        for (int off = 32; off; off >>= 1) vs += __shfl_xor(vs, off);
        float inv = rsqrtf(vs * (1.f / 128.f) + 1e-5f);
        size_t base = (size_t)grow * 128;
        hcn_ln[base + lane]      = f2bf(d0 * inv * cnn_gamma[lane]      + cnn_beta[lane]);
        hcn_ln[base + lane + 64] = f2bf(d1 * inv * cnn_gamma[lane + 64] + cnn_beta[lane + 64]);
    }
}

// ---------------- fused GAT (int8 gather) + final fuse/LN -> out ----------------
__global__ __launch_bounds__(256) void gat_final_kernel(
    const uchar_t* __restrict__ xl8t, const float* __restrict__ scales,
    const ushort_t* __restrict__ xrb,
    const int* __restrict__ srcs, const int* __restrict__ offs,
    const float* __restrict__ att, const float* __restrict__ gat_bias,
    const float* __restrict__ gat_gamma, const float* __restrict__ gat_beta,
    const ushort_t* __restrict__ hcn_ln, const ushort_t* __restrict__ resb,
    const float* __restrict__ res_b,
    const float* __restrict__ fuse_gamma, const float* __restrict__ fuse_beta,
    float* __restrict__ out, int E, int N) {
    int wid = (blockIdx.x * 256 + threadIdx.x) >> 6;
    int lane = threadIdx.x & 63;
    if (wid >= N) return;
    int d = wid;
    int h = lane >> 4;
    const uint4 rv = ((const uint4*)(xrb + (size_t)d * HF))[lane];
    float xr8[8];
    xr8[0] = bflo(rv.x); xr8[1] = bfhi(rv.x);
    xr8[2] = bflo(rv.y); xr8[3] = bfhi(rv.y);
    xr8[4] = bflo(rv.z); xr8[5] = bfhi(rv.z);
    xr8[6] = bflo(rv.w); xr8[7] = bfhi(rv.w);
    const float LOG2E = 1.44269504f;
    const float4 a0 = ((const float4*)att)[lane * 2];
    const float4 a1 = ((const float4*)att)[lane * 2 + 1];
    const float aw[8] = {a0.x * LOG2E, a0.y * LOG2E, a0.z * LOG2E, a0.w * LOG2E,
                         a1.x * LOG2E, a1.y * LOG2E, a1.z * LOG2E, a1.w * LOG2E};
    float acc[8] = {};
    float dn = 0.f, sumexs = 0.f;

    // xl_j = sc*(q_j-128); leaky0.2(v)*a = a*(0.6v+0.4|v|)
    auto process = [&](uint2 lv, float sc) {
        float qf[8];
        qf[0] = (float)(lv.x & 0xff);         qf[1] = (float)((lv.x >> 8) & 0xff);
        qf[2] = (float)((lv.x >> 16) & 0xff); qf[3] = (float)(lv.x >> 24);
        qf[4] = (float)(lv.y & 0xff);         qf[5] = (float)((lv.y >> 8) & 0xff);
        qf[6] = (float)((lv.y >> 16) & 0xff); qf[7] = (float)(lv.y >> 24);
        float c = 128.f * sc;
        float s1 = 0.f, s2 = 0.f;
        #pragma unroll
        for (int j = 0; j < 8; ++j) {
            float v = fmaf(sc, qf[j], xr8[j]) - c;
            s1 = fmaf(v, aw[j], s1);
            s2 = fmaf(fabsf(v), aw[j], s2);
        }
        float s = fmaf(0.6f, s1, 0.4f * s2);
        s = rowsum16(s);
        float ex = exp2f(s);
        float exs = ex * sc;
        dn += ex; sumexs += exs;
        #pragma unroll
        for (int j = 0; j < 8; ++j) acc[j] = fmaf(exs, qf[j], acc[j]);
    };

    process(((const uint2*)(xl8t + (size_t)d * 512))[lane],
            scales[(size_t)d * 4 + h]);   // self-loop

    int start = offs[d];
    int end = (d == N - 1) ? E : offs[d + 1];
    int p = start;
    for (; p + 3 < end; p += 4) {
        int s0 = srcs[p], s1 = srcs[p + 1], s2 = srcs[p + 2], s3 = srcs[p + 3];
        uint2 l0 = ((const uint2*)(xl8t + (size_t)s0 * 512))[lane];
        uint2 l1 = ((const uint2*)(xl8t + (size_t)s1 * 512))[lane];
        uint2 l2 = ((const uint2*)(xl8t + (size_t)s2 * 512))[lane];
        uint2 l3 = ((const uint2*)(xl8t + (size_t)s3 * 512))[lane];
        float c0 = scales[(size_t)s0 * 4 + h];
        float c1 = scales[(size_t)s1 * 4 + h];
        float c2 = scales[(size_t)s2 * 4 + h];
        float c3 = scales[(size_t)s3 * 4 + h];
        process(l0, c0); process(l1, c1); process(l2, c2); process(l3, c3);
    }
    for (; p < end; ++p) {
        int sp = srcs[p];
        process(((const uint2*)(xl8t + (size_t)sp * 512))[lane],
                scales[(size_t)sp * 4 + h]);
    }

    float inv = 1.f / dn;
    float corr = 128.f * sumexs;
    float v[8];
    #pragma unroll
    for (int j = 0; j < 8; ++j) {
        float t2 = (acc[j] - corr) * inv;
        t2 += __shfl_xor(t2, 16);
        t2 += __shfl_xor(t2, 32);
        v[j] = t2;
    }
    int col = (lane & 15) * 8 + 2 * h;
    float g0 = 0.25f * v[2 * h]     + gat_bias[col];
    float g1 = 0.25f * v[2 * h + 1] + gat_bias[col + 1];
    g0 = g0 > 0.f ? g0 : 0.01f * g0;
    g1 = g1 > 0.f ? g1 : 0.01f * g1;
    // LN(gat)
    float s = g0 + g1;
    #pragma unroll
    for (int off = 32; off; off >>= 1) s += __shfl_xor(s, off);
    float mu = s * (1.f / 128.f);
    float d0 = g0 - mu, d1 = g1 - mu;
    float vs = d0 * d0 + d1 * d1;
    #pragma unroll
    for (int off = 32; off; off >>= 1) vs += __shfl_xor(vs, off);
    float rinv = rsqrtf(vs * (1.f / 128.f) + 1e-5f);
    float hg0 = d0 * rinv * gat_gamma[col]     + gat_beta[col];
    float hg1 = d1 * rinv * gat_gamma[col + 1] + gat_beta[col + 1];
    // fuse: + hcn_ln + res + res_b, then LN(fuse)
    size_t base = (size_t)d * 128 + col;
    unsigned hcu = *(const unsigned*)(hcn_ln + base);
    unsigned rsu = *(const unsigned*)(resb + base);
    float v0 = hg0 + bflo(hcu) + bflo(rsu) + res_b[col];
    float v1 = hg1 + bfhi(hcu) + bfhi(rsu) + res_b[col + 1];
    s = v0 + v1;
    #pragma unroll
    for (int off = 32; off; off >>= 1) s += __shfl_xor(s, off);
    mu = s * (1.f / 128.f);
    d0 = v0 - mu; d1 = v1 - mu;
    vs = d0 * d0 + d1 * d1;
    #pragma unroll
    for (int off = 32; off; off >>= 1) vs += __shfl_xor(vs, off);
    rinv = rsqrtf(vs * (1.f / 128.f) + 1e-5f);
    float2 o2 = make_float2(d0 * rinv * fuse_gamma[col]     + fuse_beta[col],
                            d1 * rinv * fuse_gamma[col + 1] + fuse_beta[col + 1]);
    *(float2*)(out + base) = o2;
}

extern "C" void kernel_launch(void* const* d_in, const int* in_sizes, int n_in,
                              void* d_out, int out_size, void* d_ws, size_t ws_size,
                              hipStream_t stream) {
    const float* x         = (const float*)d_in[0];
    const int*   ei        = (const int*)d_in[1];
    const float* W_l       = (const float*)d_in[2];
    const float* W_r       = (const float*)d_in[3];
    const float* att       = (const float*)d_in[4];
    const float* gat_bias  = (const float*)d_in[5];
    const float* gat_gamma = (const float*)d_in[6];
    const float* gat_beta  = (const float*)d_in[7];
    const float* cnn_W     = (const float*)d_in[8];
    const float* cnn_b     = (const float*)d_in[9];
    const float* conv_W    = (const float*)d_in[10];
    const float* conv_b    = (const float*)d_in[11];
    const float* cnn_gamma = (const float*)d_in[12];
    const float* cnn_beta  = (const float*)d_in[13];
    const float* res_W     = (const float*)d_in[14];
    const float* res_b     = (const float*)d_in[15];
    const float* fuse_gamma= (const float*)d_in[16];
    const float* fuse_beta = (const float*)d_in[17];

    int N = in_sizes[0] / IN_F;   // 16384
    int E = in_sizes[1] / 2;      // 262144

    char* ws = (char*)d_ws;
    size_t off = 0;
    ushort_t* xb     = (ushort_t*)(ws + off); off += (size_t)N * IN_F * 2;
    ushort_t* Wt     = (ushort_t*)(ws + off); off += (size_t)NCAT * IN_F * 2;
    ushort_t* Wt2    = (ushort_t*)(ws + off); off += (size_t)7 * 128 * 128 * 2;
    uchar_t*  xl8t   = (uchar_t*)(ws + off);  off += (size_t)N * HF;        // 8MB int8
    float*    scales = (float*)(ws + off);    off += (size_t)N * 4 * 4;     // 256KB
    ushort_t* xrb    = (ushort_t*)(ws + off); off += (size_t)N * HF * 2;    // 16MB
    ushort_t* xcb    = (ushort_t*)(ws + off); off += (size_t)N * 128 * 2;
    ushort_t* resb   = (ushort_t*)(ws + off); off += (size_t)N * 128 * 2;
    ushort_t* hcn_ln = (ushort_t*)(ws + off); off += (size_t)N * 128 * 2;
    int*  counts     = (int*)(ws + off);  off += (size_t)N * 4;
    int*  offs       = (int*)(ws + off);  off += (size_t)N * 4;
    int*  cursor     = (int*)(ws + off);  off += (size_t)N * 4;
    int*  srcs       = (int*)(ws + off);  off += (size_t)E * 4;

    hipMemsetAsync(counts, 0, (size_t)N * 4, stream);

    dim3 blk(256);
    int n_cvt = N * IN_F;
    int g1 = (n_cvt / 8 + 255) / 256;
    int g2 = g1 + (NCAT * 256 + 7 * 128 * 128 + 255) / 256;
    int g3 = g2 + (E + 255) / 256;
    prep_kernel<<<g3, blk, 0, stream>>>(x, xb, n_cvt,
        W_l, W_r, cnn_W, res_W, conv_W, Wt, Wt2, ei, counts, E, g1, g2);

    scan_kernel<<<1, 1024, 0, stream>>>(counts, offs, cursor, N);
    scatter_kernel<<<(E + 255) / 256, blk, 0, stream>>>(ei, cursor, srcs, E);

    mfma_gemm<<<dim3(NCAT / 128, N / 128), blk, 0, stream>>>(
        xb, Wt, xl8t, scales, xrb, xcb, resb, N);

    conv_ln_kernel<<<dim3(16, 32), blk, 0, stream>>>(
        xcb, cnn_b, Wt2, conv_b, cnn_gamma, cnn_beta, hcn_ln);

    gat_final_kernel<<<(N + 3) / 4, blk, 0, stream>>>(
        xl8t, scales, xrb, srcs, offs, att, gat_bias, gat_gamma, gat_beta,
        hcn_ln, resb, res_b, fuse_gamma, fuse_beta, (float*)d_out, E, N);
}